// Round 1
// baseline (2983.549 us; speedup 1.0000x reference)
//
#include <hip/hip_runtime.h>
#include <math.h>

// ---- model constants (match reference) ----
#define H   128
#define H3  384
#define TC  50
#define TI  32
#define TQ  32
#define NB  128
#define NF  (NB*TC)   // 6400 fact sequences
#define EPISODES 3

__device__ __forceinline__ float dot4(float4 a, float4 b) {
  return a.x*b.x + a.y*b.y + a.z*b.z + a.w*b.w;
}
__device__ __forceinline__ float sigm(float x) { return 1.f/(1.f + expf(-x)); }
__device__ __forceinline__ float gru_comb(float ir, float iz, float inn,
                                          float hr, float hz, float hn, float h) {
  float r = sigm(ir + hr);
  float z = sigm(iz + hz);
  float n = tanhf(inn + r*hn);
  return (1.f - z)*n + z*h;
}

// =====================================================================
// Generic C[M,N] = A[M,128] @ B[N,128]^T + bias[N]   (K fixed = H = 128)
// 64x64 tile, 256 threads, 4x4 microtile with strided (r+16i) ownership
// so LDS reads are 2-way-conflict-max (free on CDNA4).
// =====================================================================
#define LDA 132
__global__ __launch_bounds__(256) void k_gemm(const float* __restrict__ A,
    const float* __restrict__ Bm, const float* __restrict__ bias,
    float* __restrict__ C, int M, int N)
{
  __shared__ float As[64][LDA];
  __shared__ float Bs[64][LDA];
  int tid = threadIdx.x;
  int bm = blockIdx.x, bn = blockIdx.y;
  #pragma unroll
  for (int i = 0; i < 8; ++i) {
    int f = tid + i*256;          // 0..2047 float4 slots (64 rows x 32 f4)
    int r = f >> 5, c4 = (f & 31)*4;
    int gr = bm*64 + r; if (gr > M-1) gr = M-1;
    *(float4*)&As[r][c4] = *(const float4*)(A + (size_t)gr*H + c4);
    int gn = bn*64 + r; if (gn > N-1) gn = N-1;
    *(float4*)&Bs[r][c4] = *(const float4*)(Bm + (size_t)gn*H + c4);
  }
  __syncthreads();
  int tr = tid & 15, tc = tid >> 4;
  float acc[4][4] = {};
  for (int k = 0; k < H; k += 4) {
    float4 a[4], b[4];
    #pragma unroll
    for (int i = 0; i < 4; ++i) a[i] = *(const float4*)&As[tr + 16*i][k];
    #pragma unroll
    for (int j = 0; j < 4; ++j) b[j] = *(const float4*)&Bs[tc + 16*j][k];
    #pragma unroll
    for (int i = 0; i < 4; ++i)
      #pragma unroll
      for (int j = 0; j < 4; ++j)
        acc[i][j] += dot4(a[i], b[j]);
  }
  __syncthreads();
  // restage C through LDS (reuse As) for coalesced global stores
  float (*Cs)[68] = (float(*)[68])(&As[0][0]);
  #pragma unroll
  for (int i = 0; i < 4; ++i)
    #pragma unroll
    for (int j = 0; j < 4; ++j)
      Cs[tr + 16*i][tc + 16*j] = acc[i][j];
  __syncthreads();
  int cr = tid >> 4, cc = (tid & 15)*4;
  #pragma unroll
  for (int rr = 0; rr < 4; ++rr) {
    int row = cr + rr*16;
    int gr = bm*64 + row;
    int gc = bn*64 + cc;
    if (gr < M) {
      if (gc + 3 < N) {
        float4 v = *(float4*)&Cs[row][cc];
        v.x += bias[gc]; v.y += bias[gc+1]; v.z += bias[gc+2]; v.w += bias[gc+3];
        *(float4*)(C + (size_t)gr*N + gc) = v;
      } else {
        #pragma unroll
        for (int j = 0; j < 4; ++j) {
          int c = gc + j;
          if (c < N) C[(size_t)gr*N + c] = Cs[row][cc + j] + bias[c];
        }
      }
    }
  }
}

// gather embedding rows for question tokens
__global__ __launch_bounds__(128) void k_gather(const float* __restrict__ embed,
    const int* __restrict__ toks, float* __restrict__ dst)
{
  int b = blockIdx.x;
  int t = toks[b];
  dst[(size_t)b*H + threadIdx.x] = embed[(size_t)t*H + threadIdx.x];
}

__global__ __launch_bounds__(256) void k_copy(const float* __restrict__ src,
    float* __restrict__ dst, int n)
{
  int i = blockIdx.x*256 + threadIdx.x;
  if (i < n) dst[i] = src[i];
}

// =====================================================================
// Fused GRU scan over `steps` timesteps; 16 sequences per block, h in LDS.
// gi comes from a precomputed table: token-indexed (toks!=null) or
// (seq*steps+t)-indexed. Emits hidden at step flen-1 (flen = #(mask==0)).
// =====================================================================
__global__ __launch_bounds__(384) void k_recgru(
    const float* __restrict__ GI, const int* __restrict__ toks,
    const int* __restrict__ masks,
    const float* __restrict__ Whh, const float* __restrict__ bhh,
    float* __restrict__ enc_out, int steps)
{
  __shared__ float hs[16][H];
  __shared__ float ghs[16][H3];
  __shared__ int enc_step[16];
  int tid = threadIdx.x;
  int seq0 = blockIdx.x * 16;
  for (int i = tid; i < 16*H; i += 384) ((float*)hs)[i] = 0.f;
  if (tid < 16) {
    int fl = 0;
    for (int i = 0; i < steps; ++i) fl += (masks[(size_t)(seq0+tid)*steps + i] == 0);
    int et = fl - 1; if (et < 0) et = 0; if (et >= steps) et = steps-1;
    enc_step[tid] = et;
  }
  __syncthreads();
  int cp = tid % 192, rg = tid / 192;     // 2 cols (cp, cp+192) x 8 rows
  int r0 = rg * 8;
  const float* w0p = Whh + (size_t)cp * H;
  const float* w1p = Whh + (size_t)(cp + 192) * H;
  float b0 = bhh[cp], b1 = bhh[cp + 192];
  for (int t = 0; t < steps; ++t) {
    float acc0[8] = {}, acc1[8] = {};
    for (int kk = 0; kk < H; kk += 16) {
      float4 wa0 = *(const float4*)(w0p + kk);
      float4 wa1 = *(const float4*)(w0p + kk + 4);
      float4 wa2 = *(const float4*)(w0p + kk + 8);
      float4 wa3 = *(const float4*)(w0p + kk + 12);
      float4 wb0 = *(const float4*)(w1p + kk);
      float4 wb1 = *(const float4*)(w1p + kk + 4);
      float4 wb2 = *(const float4*)(w1p + kk + 8);
      float4 wb3 = *(const float4*)(w1p + kk + 12);
      #pragma unroll
      for (int r = 0; r < 8; ++r) {
        const float* hp = &hs[r0 + r][kk];
        float4 h0 = *(const float4*)(hp);
        float4 h1 = *(const float4*)(hp + 4);
        float4 h2 = *(const float4*)(hp + 8);
        float4 h3 = *(const float4*)(hp + 12);
        acc0[r] += dot4(h0,wa0) + dot4(h1,wa1) + dot4(h2,wa2) + dot4(h3,wa3);
        acc1[r] += dot4(h0,wb0) + dot4(h1,wb1) + dot4(h2,wb2) + dot4(h3,wb3);
      }
    }
    #pragma unroll
    for (int r = 0; r < 8; ++r) {
      ghs[r0 + r][cp]       = acc0[r] + b0;
      ghs[r0 + r][cp + 192] = acc1[r] + b1;
    }
    __syncthreads();
    for (int idx = tid; idx < 16*H; idx += 384) {
      int r = idx >> 7, c = idx & 127;
      int seq = seq0 + r;
      const float* gir = toks ? (GI + (size_t)toks[(size_t)seq*steps + t] * H3)
                              : (GI + ((size_t)seq*steps + t) * H3);
      float h = hs[r][c];
      float hnew = gru_comb(gir[c], gir[c+H], gir[c+2*H],
                            ghs[r][c], ghs[r][c+H], ghs[r][c+2*H], h);
      hs[r][c] = hnew;
      if (t == enc_step[r]) enc_out[(size_t)seq*H + c] = hnew;
    }
    __syncthreads();
  }
}

// =====================================================================
// U1[nt][c] = (f*q)@W1a^T + |f-q|@W1c^T + b1   (m-independent gate half,
// shared by all 3 episodes)
// =====================================================================
__global__ __launch_bounds__(128) void k_gatepre(const float* __restrict__ encf,
    const float* __restrict__ qv, const float* __restrict__ W1,
    const float* __restrict__ b1, float* __restrict__ U1)
{
  __shared__ float us[16][H], vs[16][H];
  int tid = threadIdx.x;
  int nt0 = blockIdx.x * 16;
  for (int i = tid; i < 16*H; i += 128) {
    int r = i >> 7, k = i & 127;
    int nt = nt0 + r, n = nt / TC;
    float f = encf[(size_t)nt*H + k];
    float q = qv[(size_t)n*H + k];
    us[r][k] = f*q;
    vs[r][k] = fabsf(f - q);
  }
  __syncthreads();
  int c = tid;
  float acc[16] = {};
  const float* wa = W1 + (size_t)c*(4*H);        // cols 0:128   (f*q)
  const float* wc = wa + 2*H;                    // cols 256:384 (|f-q|)
  for (int kk = 0; kk < H; kk += 16) {
    float4 a0 = *(const float4*)(wa + kk);
    float4 a1 = *(const float4*)(wa + kk + 4);
    float4 a2 = *(const float4*)(wa + kk + 8);
    float4 a3 = *(const float4*)(wa + kk + 12);
    float4 c0 = *(const float4*)(wc + kk);
    float4 c1 = *(const float4*)(wc + kk + 4);
    float4 c2 = *(const float4*)(wc + kk + 8);
    float4 c3 = *(const float4*)(wc + kk + 12);
    #pragma unroll
    for (int r = 0; r < 16; ++r) {
      const float* up = &us[r][kk];
      const float* vp = &vs[r][kk];
      acc[r] += dot4(*(const float4*)up,     a0) + dot4(*(const float4*)(up+4), a1)
              + dot4(*(const float4*)(up+8), a2) + dot4(*(const float4*)(up+12),a3)
              + dot4(*(const float4*)vp,     c0) + dot4(*(const float4*)(vp+4), c1)
              + dot4(*(const float4*)(vp+8), c2) + dot4(*(const float4*)(vp+12),c3);
    }
  }
  float bb = b1[c];
  #pragma unroll
  for (int r = 0; r < 16; ++r) U1[(size_t)(nt0 + r)*H + c] = acc[r] + bb;
}

// =====================================================================
// Per-episode gates: g[nt] = sigmoid(tanh(U1 + (f*m)@W1b^T + |f-m|@W1d^T) @ W2^T + b2)
// (gates depend only on episode-start memory -> batch all 50 steps at once)
// =====================================================================
__global__ __launch_bounds__(128) void k_gate(const float* __restrict__ encf,
    const float* __restrict__ mem, const float* __restrict__ W1,
    const float* __restrict__ W2, const float* __restrict__ b2,
    const float* __restrict__ U1, float* __restrict__ gate)
{
  __shared__ float us[16][H], vs[16][H], hid[16][H], parts[16][8];
  int tid = threadIdx.x;
  int nt0 = blockIdx.x * 16;
  for (int i = tid; i < 16*H; i += 128) {
    int r = i >> 7, k = i & 127;
    int nt = nt0 + r, n = nt / TC;
    float f = encf[(size_t)nt*H + k];
    float m = mem[(size_t)n*H + k];
    us[r][k] = f*m;
    vs[r][k] = fabsf(f - m);
  }
  __syncthreads();
  int c = tid;
  float acc[16];
  #pragma unroll
  for (int r = 0; r < 16; ++r) acc[r] = U1[(size_t)(nt0 + r)*H + c];
  const float* wb = W1 + (size_t)c*(4*H) + H;     // cols 128:256 (f*m)
  const float* wd = W1 + (size_t)c*(4*H) + 3*H;   // cols 384:512 (|f-m|)
  for (int kk = 0; kk < H; kk += 16) {
    float4 a0 = *(const float4*)(wb + kk);
    float4 a1 = *(const float4*)(wb + kk + 4);
    float4 a2 = *(const float4*)(wb + kk + 8);
    float4 a3 = *(const float4*)(wb + kk + 12);
    float4 c0 = *(const float4*)(wd + kk);
    float4 c1 = *(const float4*)(wd + kk + 4);
    float4 c2 = *(const float4*)(wd + kk + 8);
    float4 c3 = *(const float4*)(wd + kk + 12);
    #pragma unroll
    for (int r = 0; r < 16; ++r) {
      const float* up = &us[r][kk];
      const float* vp = &vs[r][kk];
      acc[r] += dot4(*(const float4*)up,     a0) + dot4(*(const float4*)(up+4), a1)
              + dot4(*(const float4*)(up+8), a2) + dot4(*(const float4*)(up+12),a3)
              + dot4(*(const float4*)vp,     c0) + dot4(*(const float4*)(vp+4), c1)
              + dot4(*(const float4*)(vp+8), c2) + dot4(*(const float4*)(vp+12),c3);
    }
  }
  #pragma unroll
  for (int r = 0; r < 16; ++r) hid[r][c] = tanhf(acc[r]);
  __syncthreads();
  {
    int r = tid >> 3, i = tid & 7;
    float p = 0.f;
    for (int k = i*16; k < i*16 + 16; ++k) p += hid[r][k]*W2[k];
    parts[r][i] = p;
  }
  __syncthreads();
  if (tid < 16) {
    float s = b2[0];
    #pragma unroll
    for (int i = 0; i < 8; ++i) s += parts[tid][i];
    gate[nt0 + tid] = sigm(s);
  }
}

// =====================================================================
// One episode: 50-step gated attention GRU (2 batch rows per block) +
// final memory GRU (me_*). All row-independent across batch.
// =====================================================================
__global__ __launch_bounds__(384) void k_episode(const float* __restrict__ GIat,
    const float* __restrict__ gate,
    const float* __restrict__ at_Whh, const float* __restrict__ at_bhh,
    const float* __restrict__ me_Wih, const float* __restrict__ me_Whh,
    const float* __restrict__ me_bih, const float* __restrict__ me_bhh,
    float* __restrict__ mem)
{
  __shared__ float hs[2][H], ms[2][H], ghs[2][H3], gis[2][H3];
  int tid = threadIdx.x;
  int n0 = blockIdx.x * 2;
  if (tid < 256) {
    int r = tid >> 7, c = tid & 127;
    hs[r][c] = 0.f;
    ms[r][c] = mem[(size_t)(n0 + r)*H + c];
  }
  __syncthreads();
  const float* wp = at_Whh + (size_t)tid*H;
  float bh = at_bhh[tid];
  for (int t = 0; t < TC; ++t) {
    float a0 = 0.f, a1 = 0.f;
    for (int kk = 0; kk < H; kk += 16) {
      float4 w0 = *(const float4*)(wp + kk);
      float4 w1 = *(const float4*)(wp + kk + 4);
      float4 w2 = *(const float4*)(wp + kk + 8);
      float4 w3 = *(const float4*)(wp + kk + 12);
      const float* h0p = &hs[0][kk];
      const float* h1p = &hs[1][kk];
      a0 += dot4(*(const float4*)h0p,     w0) + dot4(*(const float4*)(h0p+4), w1)
          + dot4(*(const float4*)(h0p+8), w2) + dot4(*(const float4*)(h0p+12),w3);
      a1 += dot4(*(const float4*)h1p,     w0) + dot4(*(const float4*)(h1p+4), w1)
          + dot4(*(const float4*)(h1p+8), w2) + dot4(*(const float4*)(h1p+12),w3);
    }
    ghs[0][tid] = a0 + bh;
    ghs[1][tid] = a1 + bh;
    __syncthreads();
    if (tid < 256) {
      int r = tid >> 7, c = tid & 127;
      size_t nt = (size_t)(n0 + r)*TC + t;
      const float* gir = GIat + nt*H3;
      float h = hs[r][c];
      float h2 = gru_comb(gir[c], gir[c+H], gir[c+2*H],
                          ghs[r][c], ghs[r][c+H], ghs[r][c+2*H], h);
      float g = gate[nt];
      hs[r][c] = g*h2 + (1.f - g)*h;
    }
    __syncthreads();
  }
  // memory = GRUcell(e = hs, m = ms) with me_* weights
  {
    const float* wip = me_Wih + (size_t)tid*H;
    const float* whp = me_Whh + (size_t)tid*H;
    float ai0=0.f, ai1=0.f, ah0=0.f, ah1=0.f;
    for (int kk = 0; kk < H; kk += 16) {
      float4 i0 = *(const float4*)(wip + kk);
      float4 i1 = *(const float4*)(wip + kk + 4);
      float4 i2 = *(const float4*)(wip + kk + 8);
      float4 i3 = *(const float4*)(wip + kk + 12);
      float4 o0 = *(const float4*)(whp + kk);
      float4 o1 = *(const float4*)(whp + kk + 4);
      float4 o2 = *(const float4*)(whp + kk + 8);
      float4 o3 = *(const float4*)(whp + kk + 12);
      const float* e0 = &hs[0][kk]; const float* e1 = &hs[1][kk];
      const float* m0 = &ms[0][kk]; const float* m1 = &ms[1][kk];
      ai0 += dot4(*(const float4*)e0,     i0) + dot4(*(const float4*)(e0+4), i1)
           + dot4(*(const float4*)(e0+8), i2) + dot4(*(const float4*)(e0+12),i3);
      ai1 += dot4(*(const float4*)e1,     i0) + dot4(*(const float4*)(e1+4), i1)
           + dot4(*(const float4*)(e1+8), i2) + dot4(*(const float4*)(e1+12),i3);
      ah0 += dot4(*(const float4*)m0,     o0) + dot4(*(const float4*)(m0+4), o1)
           + dot4(*(const float4*)(m0+8), o2) + dot4(*(const float4*)(m0+12),o3);
      ah1 += dot4(*(const float4*)m1,     o0) + dot4(*(const float4*)(m1+4), o1)
           + dot4(*(const float4*)(m1+8), o2) + dot4(*(const float4*)(m1+12),o3);
    }
    gis[0][tid] = ai0 + me_bih[tid];
    gis[1][tid] = ai1 + me_bih[tid];
    ghs[0][tid] = ah0 + me_bhh[tid];
    ghs[1][tid] = ah1 + me_bhh[tid];
    __syncthreads();
    if (tid < 256) {
      int r = tid >> 7, c = tid & 127;
      float mnew = gru_comb(gis[r][c], gis[r][c+H], gis[r][c+2*H],
                            ghs[r][c], ghs[r][c+H], ghs[r][c+2*H], ms[r][c]);
      mem[(size_t)(n0 + r)*H + c] = mnew;
    }
  }
}

// =====================================================================
// Decoder recurrence: yq = [embed[2], q] fixed -> gi computed once;
// 8 steps of GRU with an_*; stores h2 per step (rows ordered n*ND + t).
// =====================================================================
__global__ __launch_bounds__(384) void k_decode(const float* __restrict__ embed,
    const float* __restrict__ qv, const float* __restrict__ mem,
    const float* __restrict__ an_Wih, const float* __restrict__ an_Whh,
    const float* __restrict__ an_bih, const float* __restrict__ an_bhh,
    float* __restrict__ h2d, int ND)
{
  __shared__ float hs[2][H], qs[2][H], e2[H], ghs[2][H3], gis[2][H3];
  int tid = threadIdx.x;
  int n0 = blockIdx.x * 2;
  if (tid < H) e2[tid] = embed[2*H + tid];
  if (tid < 256) {
    int r = tid >> 7, c = tid & 127;
    hs[r][c] = mem[(size_t)(n0 + r)*H + c];
    qs[r][c] = qv[(size_t)(n0 + r)*H + c];
  }
  __syncthreads();
  {
    const float* wp = an_Wih + (size_t)tid*(2*H);
    float se = 0.f, sq0 = 0.f, sq1 = 0.f;
    for (int kk = 0; kk < H; kk += 16) {
      float4 w0 = *(const float4*)(wp + kk);
      float4 w1 = *(const float4*)(wp + kk + 4);
      float4 w2 = *(const float4*)(wp + kk + 8);
      float4 w3 = *(const float4*)(wp + kk + 12);
      const float* ep = &e2[kk];
      se += dot4(*(const float4*)ep,     w0) + dot4(*(const float4*)(ep+4), w1)
          + dot4(*(const float4*)(ep+8), w2) + dot4(*(const float4*)(ep+12),w3);
      float4 u0 = *(const float4*)(wp + H + kk);
      float4 u1 = *(const float4*)(wp + H + kk + 4);
      float4 u2 = *(const float4*)(wp + H + kk + 8);
      float4 u3 = *(const float4*)(wp + H + kk + 12);
      const float* q0 = &qs[0][kk];
      const float* q1 = &qs[1][kk];
      sq0 += dot4(*(const float4*)q0,     u0) + dot4(*(const float4*)(q0+4), u1)
           + dot4(*(const float4*)(q0+8), u2) + dot4(*(const float4*)(q0+12),u3);
      sq1 += dot4(*(const float4*)q1,     u0) + dot4(*(const float4*)(q1+4), u1)
           + dot4(*(const float4*)(q1+8), u2) + dot4(*(const float4*)(q1+12),u3);
    }
    float b = an_bih[tid];
    gis[0][tid] = b + se + sq0;
    gis[1][tid] = b + se + sq1;
  }
  const float* whp = an_Whh + (size_t)tid*H;
  float bh = an_bhh[tid];
  for (int t = 0; t < ND; ++t) {
    float a0 = 0.f, a1 = 0.f;
    for (int kk = 0; kk < H; kk += 16) {
      float4 w0 = *(const float4*)(whp + kk);
      float4 w1 = *(const float4*)(whp + kk + 4);
      float4 w2 = *(const float4*)(whp + kk + 8);
      float4 w3 = *(const float4*)(whp + kk + 12);
      const float* h0p = &hs[0][kk];
      const float* h1p = &hs[1][kk];
      a0 += dot4(*(const float4*)h0p,     w0) + dot4(*(const float4*)(h0p+4), w1)
          + dot4(*(const float4*)(h0p+8), w2) + dot4(*(const float4*)(h0p+12),w3);
      a1 += dot4(*(const float4*)h1p,     w0) + dot4(*(const float4*)(h1p+4), w1)
          + dot4(*(const float4*)(h1p+8), w2) + dot4(*(const float4*)(h1p+12),w3);
    }
    ghs[0][tid] = a0 + bh;
    ghs[1][tid] = a1 + bh;
    __syncthreads();
    if (tid < 256) {
      int r = tid >> 7, c = tid & 127;
      float h2 = gru_comb(gis[r][c], gis[r][c+H], gis[r][c+2*H],
                          ghs[r][c], ghs[r][c+H], ghs[r][c+2*H], hs[r][c]);
      hs[r][c] = h2;
      h2d[((size_t)(n0 + r)*ND + t)*H + c] = h2;
    }
    __syncthreads();
  }
}

// per-row online max + sum(exp) -> lse
__global__ __launch_bounds__(256) void k_rowstat(const float* __restrict__ C, int V,
                                                 float* __restrict__ lse)
{
  __shared__ float mred[256], sred[256];
  int tid = threadIdx.x;
  const float* row = C + (size_t)blockIdx.x * V;
  float m = -3.402823466e38f, s = 0.f;
  for (int i = tid; i < V; i += 256) {
    float x = row[i];
    if (x > m) { s = s * expf(m - x) + 1.f; m = x; }
    else s += expf(x - m);
  }
  mred[tid] = m; sred[tid] = s;
  __syncthreads();
  for (int off = 128; off > 0; off >>= 1) {
    if (tid < off) {
      float m1 = mred[tid], s1 = sred[tid];
      float m2 = mred[tid + off], s2 = sred[tid + off];
      float M = fmaxf(m1, m2);
      sred[tid] = s1*expf(m1 - M) + s2*expf(m2 - M);
      mred[tid] = M;
    }
    __syncthreads();
  }
  if (tid == 0) lse[blockIdx.x] = mred[0] + logf(sred[0]);
}

__global__ __launch_bounds__(256) void k_sub(float* __restrict__ C,
    const float* __restrict__ lse, int V, long long tot4)
{
  long long i = (long long)blockIdx.x*256 + threadIdx.x;
  if (i >= tot4) return;
  float4* C4 = (float4*)C;
  float4 v = C4[i];
  int row = (int)((i*4) / V);
  float l = lse[row];
  v.x -= l; v.y -= l; v.z -= l; v.w -= l;
  C4[i] = v;
}

// =====================================================================
extern "C" void kernel_launch(void* const* d_in, const int* in_sizes, int n_in,
                              void* d_out, int out_size, void* d_ws, size_t ws_size,
                              hipStream_t stream) {
  const int*   facts     = (const int*)  d_in[0];
  const int*   fmask     = (const int*)  d_in[1];
  const int*   questions = (const int*)  d_in[2];
  const int*   qmask     = (const int*)  d_in[3];
  // d_in[4] = num_decode (device scalar); derived from out_size instead.
  const float* embed     = (const float*)d_in[5];
  const float* ig_Wih    = (const float*)d_in[6];
  const float* ig_Whh    = (const float*)d_in[7];
  const float* ig_bih    = (const float*)d_in[8];
  const float* ig_bhh    = (const float*)d_in[9];
  const float* qg_Wih    = (const float*)d_in[10];
  const float* qg_Whh    = (const float*)d_in[11];
  const float* qg_bih    = (const float*)d_in[12];
  const float* qg_bhh    = (const float*)d_in[13];
  const float* at_Wih    = (const float*)d_in[14];
  const float* at_Whh    = (const float*)d_in[15];
  const float* at_bih    = (const float*)d_in[16];
  const float* at_bhh    = (const float*)d_in[17];
  const float* me_Wih    = (const float*)d_in[18];
  const float* me_Whh    = (const float*)d_in[19];
  const float* me_bih    = (const float*)d_in[20];
  const float* me_bhh    = (const float*)d_in[21];
  const float* an_Wih    = (const float*)d_in[22];
  const float* an_Whh    = (const float*)d_in[23];
  const float* an_bih    = (const float*)d_in[24];
  const float* an_bhh    = (const float*)d_in[25];
  const float* gate_W1   = (const float*)d_in[26];
  const float* gate_b1   = (const float*)d_in[27];
  const float* gate_W2   = (const float*)d_in[28];
  const float* gate_b2   = (const float*)d_in[29];
  const float* fc_W      = (const float*)d_in[30];
  const float* fc_b      = (const float*)d_in[31];
  (void)n_in; (void)ws_size;

  const int V  = in_sizes[5] / H;          // 50000
  const int ND = out_size / (NB * V);      // 8

  float* OUT = (float*)d_out;
  // d_out doubles as scratch for everything dead before the logits GEMM.
  size_t oP    = 0;
  size_t oEMBQ = (size_t)V * H3;                  // 19.2M
  size_t oQGI  = oEMBQ + (size_t)NB*TQ*H;         // +0.52M
  size_t oGIAT = oQGI  + (size_t)NB*TQ*H3;        // +1.57M
  size_t oU1   = oGIAT + (size_t)NF*H3;           // +2.46M
  size_t oGATE = oU1   + (size_t)NF*H;            // +0.82M  (total ~24.6M < 51.2M)
  float* P    = OUT + oP;
  float* EMBQ = OUT + oEMBQ;
  float* QGI  = OUT + oQGI;
  float* GIAT = OUT + oGIAT;
  float* U1b  = OUT + oU1;
  float* GATE = OUT + oGATE;

  float* encf = (float*)d_ws;              // NF*H
  float* qvec = encf + (size_t)NF*H;       // NB*H
  float* mem  = qvec + (size_t)NB*H;       // NB*H
  float* h2d  = mem  + (size_t)NB*H;       // NB*ND*H
  float* lse  = h2d  + (size_t)NB*ND*H;    // NB*ND

  // 1. fact-GRU input projection as vocab table: P = embed @ ig_Wih^T + ig_bih
  k_gemm<<<dim3((V+63)/64, H3/64), 256, 0, stream>>>(embed, ig_Wih, ig_bih, P, V, H3);
  // 2-3. question embeddings + projection
  k_gather<<<NB*TQ, 128, 0, stream>>>(embed, questions, EMBQ);
  k_gemm<<<dim3((NB*TQ+63)/64, H3/64), 256, 0, stream>>>(EMBQ, qg_Wih, qg_bih, QGI, NB*TQ, H3);
  // 4. fact GRU scan (6400 seqs x 32 steps)
  k_recgru<<<NF/16, 384, 0, stream>>>(P, facts, fmask, ig_Whh, ig_bhh, encf, TI);
  // 5. question GRU scan (128 seqs x 32 steps)
  k_recgru<<<NB/16, 384, 0, stream>>>(QGI, nullptr, qmask, qg_Whh, qg_bhh, qvec, TQ);
  // 6. attention-GRU input projection for all facts
  k_gemm<<<dim3(NF/64, H3/64), 256, 0, stream>>>(encf, at_Wih, at_bih, GIAT, NF, H3);
  // 7. m-independent gate half (shared across episodes)
  k_gatepre<<<NF/16, 128, 0, stream>>>(encf, qvec, gate_W1, gate_b1, U1b);
  // 8. memory = q
  k_copy<<<(NB*H+255)/256, 256, 0, stream>>>(qvec, mem, NB*H);
  // 9. episodes
  for (int e = 0; e < EPISODES; ++e) {
    k_gate<<<NF/16, 128, 0, stream>>>(encf, mem, gate_W1, gate_W2, gate_b2, U1b, GATE);
    k_episode<<<NB/2, 384, 0, stream>>>(GIAT, GATE, at_Whh, at_bhh,
                                        me_Wih, me_Whh, me_bih, me_bhh, mem);
  }
  // 10. decoder recurrence
  k_decode<<<NB/2, 384, 0, stream>>>(embed, qvec, mem, an_Wih, an_Whh, an_bih, an_bhh,
                                     h2d, ND);
  // 11. logits = h2 @ fc_W^T + fc_b  (overwrites all of d_out)
  k_gemm<<<dim3((NB*ND+63)/64, (V+63)/64), 256, 0, stream>>>(h2d, fc_W, fc_b, OUT, NB*ND, V);
  // 12-13. log_softmax
  k_rowstat<<<NB*ND, 256, 0, stream>>>(OUT, V, lse);
  long long tot4 = (long long)NB*ND*V/4;
  k_sub<<<(unsigned)((tot4 + 255)/256), 256, 0, stream>>>(OUT, lse, V, tot4);
}

// Round 2
// 1463.718 us; speedup vs baseline: 2.0383x; 2.0383x over previous
//
#include <hip/hip_runtime.h>
#include <math.h>

// ---- model constants (match reference) ----
#define H   128
#define H3  384
#define TC  50
#define TI  32
#define TQ  32
#define NB  128
#define NF  (NB*TC)   // 6400 fact sequences
#define EPISODES 3

typedef short  bf16x8 __attribute__((ext_vector_type(8)));
typedef float  f32x4  __attribute__((ext_vector_type(4)));

__device__ __forceinline__ float dot4(float4 a, float4 b) {
  return a.x*b.x + a.y*b.y + a.z*b.z + a.w*b.w;
}
__device__ __forceinline__ float sigm(float x) { return 1.f/(1.f + expf(-x)); }
__device__ __forceinline__ float gru_comb(float ir, float iz, float inn,
                                          float hr, float hz, float hn, float h) {
  float r = sigm(ir + hr);
  float z = sigm(iz + hz);
  float n = tanhf(inn + r*hn);
  return (1.f - z)*n + z*h;
}
__device__ __forceinline__ short f2bf(float x) {   // RNE f32 -> bf16
  union { float f; unsigned u; } v; v.f = x;
  unsigned r = v.u + 0x7fffu + ((v.u >> 16) & 1u);
  return (short)(r >> 16);
}
__device__ __forceinline__ bf16x8 pack8(float4 lo, float4 hi) {
  bf16x8 o;
  o[0]=f2bf(lo.x); o[1]=f2bf(lo.y); o[2]=f2bf(lo.z); o[3]=f2bf(lo.w);
  o[4]=f2bf(hi.x); o[5]=f2bf(hi.y); o[6]=f2bf(hi.z); o[7]=f2bf(hi.w);
  return o;
}

// =====================================================================
// MFMA GEMM: C[M,N] = A[M,128] @ B[N,128]^T + bias[N]  (fp32 in/out,
// bf16 staged in LDS, K=128 = 4 mfma k-frags, no K-loop).
// Block: 256 thr (4 waves), tile M=64 x N=128. wave w -> M-rows w*16..+15.
// =====================================================================
#define GM_LDA 136
__global__ __launch_bounds__(256) void k_mgemm(const float* __restrict__ A,
    const float* __restrict__ Bm, const float* __restrict__ bias,
    float* __restrict__ C, int M, int N)
{
  __shared__ __align__(16) short As[64][GM_LDA];
  __shared__ __align__(16) short Bs[128][GM_LDA];
  int tid = threadIdx.x;
  int lane = tid & 63, wave = tid >> 6;
  int bm = blockIdx.x, bn = blockIdx.y;
  #pragma unroll
  for (int i = 0; i < 4; ++i) {              // A: 1024 chunks of 8 elems
    int ch = tid + i*256;
    int r = ch >> 4, e = (ch & 15)*8;
    int gr = bm*64 + r; if (gr > M-1) gr = M-1;
    const float* src = A + (size_t)gr*H + e;
    *(bf16x8*)&As[r][e] = pack8(*(const float4*)src, *(const float4*)(src+4));
  }
  #pragma unroll
  for (int i = 0; i < 8; ++i) {              // B: 2048 chunks
    int ch = tid + i*256;
    int r = ch >> 4, e = (ch & 15)*8;
    int gn = bn*128 + r; if (gn > N-1) gn = N-1;
    const float* src = Bm + (size_t)gn*H + e;
    *(bf16x8*)&Bs[r][e] = pack8(*(const float4*)src, *(const float4*)(src+4));
  }
  __syncthreads();
  int q = lane >> 4, l15 = lane & 15;
  f32x4 acc[8];
  #pragma unroll
  for (int nt = 0; nt < 8; ++nt) { acc[nt][0]=0.f; acc[nt][1]=0.f; acc[nt][2]=0.f; acc[nt][3]=0.f; }
  int mrow = wave*16 + l15;
  #pragma unroll
  for (int kf = 0; kf < 4; ++kf) {
    bf16x8 a = *(bf16x8*)&As[mrow][q*8 + kf*32];
    #pragma unroll
    for (int nt = 0; nt < 8; ++nt) {
      bf16x8 b = *(bf16x8*)&Bs[nt*16 + l15][q*8 + kf*32];
      acc[nt] = __builtin_amdgcn_mfma_f32_16x16x32_bf16(a, b, acc[nt], 0, 0, 0);
    }
  }
  #pragma unroll
  for (int nt = 0; nt < 8; ++nt) {
    int col = bn*128 + nt*16 + l15;
    if (col < N) {
      float bv = bias[col];
      #pragma unroll
      for (int reg = 0; reg < 4; ++reg) {
        int row = bm*64 + wave*16 + q*4 + reg;
        if (row < M) C[(size_t)row*N + col] = acc[nt][reg] + bv;
      }
    }
  }
}

// gather embedding rows for question tokens
__global__ __launch_bounds__(128) void k_gather(const float* __restrict__ embed,
    const int* __restrict__ toks, float* __restrict__ dst)
{
  int b = blockIdx.x;
  int t = toks[b];
  dst[(size_t)b*H + threadIdx.x] = embed[(size_t)t*H + threadIdx.x];
}

__global__ __launch_bounds__(256) void k_copy(const float* __restrict__ src,
    float* __restrict__ dst, int n)
{
  int i = blockIdx.x*256 + threadIdx.x;
  if (i < n) dst[i] = src[i];
}

// =====================================================================
// Fused GRU scan, MFMA edition. 16 sequences/block, 256 threads (4 waves).
// - h kept fp32 (hsf) + bf16 copy (hsb) for the MFMA A-operand.
// - Whh fragments preloaded to registers (bf16), wave w owns cols 96w..96w+95.
// - next-step gi gathered into registers during the matmul phase.
// gi table includes bih. Emits hidden at step flen-1 (flen = #(mask==0)).
// =====================================================================
__global__ __launch_bounds__(256) void k_recgru(
    const float* __restrict__ GI, const int* __restrict__ toks,
    const int* __restrict__ masks,
    const float* __restrict__ Whh, const float* __restrict__ bhh,
    float* __restrict__ enc_out, int steps)
{
  __shared__ float hsf[16][H];                       // fp32 master h
  __shared__ __align__(16) short hsb[16][136];       // bf16 h (padded row)
  __shared__ float ghs[16][388];                     // gh (no bias) fp32
  __shared__ int   ltoks[16*TI];
  __shared__ int   enc_step[16];
  int tid = threadIdx.x;
  int lane = tid & 63, wave = tid >> 6;
  int q = lane >> 4, l15 = lane & 15;
  int seq0 = blockIdx.x * 16;

  for (int i = tid; i < 16*H;   i += 256) ((float*)hsf)[i] = 0.f;
  for (int i = tid; i < 16*136; i += 256) ((short*)hsb)[i] = 0;
  if (toks) for (int i = tid; i < 16*steps; i += 256)
    ltoks[i] = toks[(size_t)seq0*steps + i];
  if (tid < 16) {
    int fl = 0;
    for (int i = 0; i < steps; ++i) fl += (masks[(size_t)(seq0+tid)*steps + i] == 0);
    int et = fl - 1; if (et < 0) et = 0; if (et >= steps) et = steps-1;
    enc_step[tid] = et;
  }
  // per-wave weight fragments: B[k][n] = Whh[n][k], lane&15 -> n, quad*8+j -> k
  bf16x8 wfrag[6][4];
  #pragma unroll
  for (int nt = 0; nt < 6; ++nt) {
    int n = wave*96 + nt*16 + l15;
    const float* wr = Whh + (size_t)n*H + q*8;
    #pragma unroll
    for (int kf = 0; kf < 4; ++kf)
      wfrag[nt][kf] = pack8(*(const float4*)(wr + kf*32), *(const float4*)(wr + kf*32 + 4));
  }
  int c = tid & 127;
  int rbase = tid >> 7;                              // elementwise rows rbase+2i
  float bh0 = bhh[c], bh1 = bhh[c+H], bh2 = bhh[c+2*H];
  __syncthreads();

  // prefetch gi(0)
  float cr_[8], cz_[8], cn_[8], nr_[8], nz_[8], nn_[8];
  #pragma unroll
  for (int i = 0; i < 8; ++i) {
    int r = rbase + 2*i;
    size_t rowid = toks ? (size_t)ltoks[r*steps] : ((size_t)(seq0 + r)*steps);
    const float* g = GI + rowid*H3 + c;
    cr_[i] = g[0]; cz_[i] = g[H]; cn_[i] = g[2*H];
  }

  for (int t = 0; t < steps; ++t) {
    // issue next-step gathers early (latency hidden under MFMA)
    if (t + 1 < steps) {
      #pragma unroll
      for (int i = 0; i < 8; ++i) {
        int r = rbase + 2*i;
        size_t rowid = toks ? (size_t)ltoks[r*steps + t + 1]
                            : ((size_t)(seq0 + r)*steps + t + 1);
        const float* g = GI + rowid*H3 + c;
        nr_[i] = g[0]; nz_[i] = g[H]; nn_[i] = g[2*H];
      }
    }
    // gh = h @ Whh^T  via MFMA
    f32x4 acc[6];
    #pragma unroll
    for (int nt = 0; nt < 6; ++nt) { acc[nt][0]=0.f; acc[nt][1]=0.f; acc[nt][2]=0.f; acc[nt][3]=0.f; }
    #pragma unroll
    for (int kf = 0; kf < 4; ++kf) {
      bf16x8 a = *(bf16x8*)&hsb[l15][q*8 + kf*32];
      #pragma unroll
      for (int nt = 0; nt < 6; ++nt)
        acc[nt] = __builtin_amdgcn_mfma_f32_16x16x32_bf16(a, wfrag[nt][kf], acc[nt], 0, 0, 0);
    }
    #pragma unroll
    for (int nt = 0; nt < 6; ++nt) {
      int col = wave*96 + nt*16 + l15;
      #pragma unroll
      for (int reg = 0; reg < 4; ++reg)
        ghs[q*4 + reg][col] = acc[nt][reg];
    }
    __syncthreads();
    // elementwise GRU update
    #pragma unroll
    for (int i = 0; i < 8; ++i) {
      int r = rbase + 2*i;
      float h = hsf[r][c];
      float hnew = gru_comb(cr_[i], cz_[i], cn_[i],
                            ghs[r][c] + bh0, ghs[r][c+H] + bh1, ghs[r][c+2*H] + bh2, h);
      hsf[r][c] = hnew;
      hsb[r][c] = f2bf(hnew);
      if (t == enc_step[r]) enc_out[(size_t)(seq0 + r)*H + c] = hnew;
    }
    __syncthreads();
    #pragma unroll
    for (int i = 0; i < 8; ++i) { cr_[i] = nr_[i]; cz_[i] = nz_[i]; cn_[i] = nn_[i]; }
  }
}

// =====================================================================
// U1[nt][c] = (f*q)@W1a^T + |f-q|@W1c^T + b1   (m-independent gate half)
// =====================================================================
__global__ __launch_bounds__(128) void k_gatepre(const float* __restrict__ encf,
    const float* __restrict__ qv, const float* __restrict__ W1,
    const float* __restrict__ b1, float* __restrict__ U1)
{
  __shared__ float us[16][H], vs[16][H];
  int tid = threadIdx.x;
  int nt0 = blockIdx.x * 16;
  for (int i = tid; i < 16*H; i += 128) {
    int r = i >> 7, k = i & 127;
    int nt = nt0 + r, n = nt / TC;
    float f = encf[(size_t)nt*H + k];
    float q = qv[(size_t)n*H + k];
    us[r][k] = f*q;
    vs[r][k] = fabsf(f - q);
  }
  __syncthreads();
  int c = tid;
  float acc[16] = {};
  const float* wa = W1 + (size_t)c*(4*H);
  const float* wc = wa + 2*H;
  for (int kk = 0; kk < H; kk += 16) {
    float4 a0 = *(const float4*)(wa + kk);
    float4 a1 = *(const float4*)(wa + kk + 4);
    float4 a2 = *(const float4*)(wa + kk + 8);
    float4 a3 = *(const float4*)(wa + kk + 12);
    float4 c0 = *(const float4*)(wc + kk);
    float4 c1 = *(const float4*)(wc + kk + 4);
    float4 c2 = *(const float4*)(wc + kk + 8);
    float4 c3 = *(const float4*)(wc + kk + 12);
    #pragma unroll
    for (int r = 0; r < 16; ++r) {
      const float* up = &us[r][kk];
      const float* vp = &vs[r][kk];
      acc[r] += dot4(*(const float4*)up,     a0) + dot4(*(const float4*)(up+4), a1)
              + dot4(*(const float4*)(up+8), a2) + dot4(*(const float4*)(up+12),a3)
              + dot4(*(const float4*)vp,     c0) + dot4(*(const float4*)(vp+4), c1)
              + dot4(*(const float4*)(vp+8), c2) + dot4(*(const float4*)(vp+12),c3);
    }
  }
  float bb = b1[c];
  #pragma unroll
  for (int r = 0; r < 16; ++r) U1[(size_t)(nt0 + r)*H + c] = acc[r] + bb;
}

// =====================================================================
// Per-episode gates (episode-start memory -> batch all 50 steps)
// =====================================================================
__global__ __launch_bounds__(128) void k_gate(const float* __restrict__ encf,
    const float* __restrict__ mem, const float* __restrict__ W1,
    const float* __restrict__ W2, const float* __restrict__ b2,
    const float* __restrict__ U1, float* __restrict__ gate)
{
  __shared__ float us[16][H], vs[16][H], hid[16][H], parts[16][8];
  int tid = threadIdx.x;
  int nt0 = blockIdx.x * 16;
  for (int i = tid; i < 16*H; i += 128) {
    int r = i >> 7, k = i & 127;
    int nt = nt0 + r, n = nt / TC;
    float f = encf[(size_t)nt*H + k];
    float m = mem[(size_t)n*H + k];
    us[r][k] = f*m;
    vs[r][k] = fabsf(f - m);
  }
  __syncthreads();
  int c = tid;
  float acc[16];
  #pragma unroll
  for (int r = 0; r < 16; ++r) acc[r] = U1[(size_t)(nt0 + r)*H + c];
  const float* wb = W1 + (size_t)c*(4*H) + H;
  const float* wd = W1 + (size_t)c*(4*H) + 3*H;
  for (int kk = 0; kk < H; kk += 16) {
    float4 a0 = *(const float4*)(wb + kk);
    float4 a1 = *(const float4*)(wb + kk + 4);
    float4 a2 = *(const float4*)(wb + kk + 8);
    float4 a3 = *(const float4*)(wb + kk + 12);
    float4 c0 = *(const float4*)(wd + kk);
    float4 c1 = *(const float4*)(wd + kk + 4);
    float4 c2 = *(const float4*)(wd + kk + 8);
    float4 c3 = *(const float4*)(wd + kk + 12);
    #pragma unroll
    for (int r = 0; r < 16; ++r) {
      const float* up = &us[r][kk];
      const float* vp = &vs[r][kk];
      acc[r] += dot4(*(const float4*)up,     a0) + dot4(*(const float4*)(up+4), a1)
              + dot4(*(const float4*)(up+8), a2) + dot4(*(const float4*)(up+12),a3)
              + dot4(*(const float4*)vp,     c0) + dot4(*(const float4*)(vp+4), c1)
              + dot4(*(const float4*)(vp+8), c2) + dot4(*(const float4*)(vp+12),c3);
    }
  }
  #pragma unroll
  for (int r = 0; r < 16; ++r) hid[r][c] = tanhf(acc[r]);
  __syncthreads();
  {
    int r = tid >> 3, i = tid & 7;
    float p = 0.f;
    for (int k = i*16; k < i*16 + 16; ++k) p += hid[r][k]*W2[k];
    parts[r][i] = p;
  }
  __syncthreads();
  if (tid < 16) {
    float s = b2[0];
    #pragma unroll
    for (int i = 0; i < 8; ++i) s += parts[tid][i];
    gate[nt0 + tid] = sigm(s);
  }
}

// =====================================================================
// One episode: 50-step gated attention GRU (2 batch rows/block) + memory GRU
// =====================================================================
__global__ __launch_bounds__(384) void k_episode(const float* __restrict__ GIat,
    const float* __restrict__ gate,
    const float* __restrict__ at_Whh, const float* __restrict__ at_bhh,
    const float* __restrict__ me_Wih, const float* __restrict__ me_Whh,
    const float* __restrict__ me_bih, const float* __restrict__ me_bhh,
    float* __restrict__ mem)
{
  __shared__ float hs[2][H], ms[2][H], ghs[2][H3], gis[2][H3];
  int tid = threadIdx.x;
  int n0 = blockIdx.x * 2;
  if (tid < 256) {
    int r = tid >> 7, c = tid & 127;
    hs[r][c] = 0.f;
    ms[r][c] = mem[(size_t)(n0 + r)*H + c];
  }
  __syncthreads();
  const float* wp = at_Whh + (size_t)tid*H;
  float bh = at_bhh[tid];
  for (int t = 0; t < TC; ++t) {
    float a0 = 0.f, a1 = 0.f;
    for (int kk = 0; kk < H; kk += 16) {
      float4 w0 = *(const float4*)(wp + kk);
      float4 w1 = *(const float4*)(wp + kk + 4);
      float4 w2 = *(const float4*)(wp + kk + 8);
      float4 w3 = *(const float4*)(wp + kk + 12);
      const float* h0p = &hs[0][kk];
      const float* h1p = &hs[1][kk];
      a0 += dot4(*(const float4*)h0p,     w0) + dot4(*(const float4*)(h0p+4), w1)
          + dot4(*(const float4*)(h0p+8), w2) + dot4(*(const float4*)(h0p+12),w3);
      a1 += dot4(*(const float4*)h1p,     w0) + dot4(*(const float4*)(h1p+4), w1)
          + dot4(*(const float4*)(h1p+8), w2) + dot4(*(const float4*)(h1p+12),w3);
    }
    ghs[0][tid] = a0 + bh;
    ghs[1][tid] = a1 + bh;
    __syncthreads();
    if (tid < 256) {
      int r = tid >> 7, c = tid & 127;
      size_t nt = (size_t)(n0 + r)*TC + t;
      const float* gir = GIat + nt*H3;
      float h = hs[r][c];
      float h2 = gru_comb(gir[c], gir[c+H], gir[c+2*H],
                          ghs[r][c], ghs[r][c+H], ghs[r][c+2*H], h);
      float g = gate[nt];
      hs[r][c] = g*h2 + (1.f - g)*h;
    }
    __syncthreads();
  }
  {
    const float* wip = me_Wih + (size_t)tid*H;
    const float* whp = me_Whh + (size_t)tid*H;
    float ai0=0.f, ai1=0.f, ah0=0.f, ah1=0.f;
    for (int kk = 0; kk < H; kk += 16) {
      float4 i0 = *(const float4*)(wip + kk);
      float4 i1 = *(const float4*)(wip + kk + 4);
      float4 i2 = *(const float4*)(wip + kk + 8);
      float4 i3 = *(const float4*)(wip + kk + 12);
      float4 o0 = *(const float4*)(whp + kk);
      float4 o1 = *(const float4*)(whp + kk + 4);
      float4 o2 = *(const float4*)(whp + kk + 8);
      float4 o3 = *(const float4*)(whp + kk + 12);
      const float* e0 = &hs[0][kk]; const float* e1 = &hs[1][kk];
      const float* m0 = &ms[0][kk]; const float* m1 = &ms[1][kk];
      ai0 += dot4(*(const float4*)e0,     i0) + dot4(*(const float4*)(e0+4), i1)
           + dot4(*(const float4*)(e0+8), i2) + dot4(*(const float4*)(e0+12),i3);
      ai1 += dot4(*(const float4*)e1,     i0) + dot4(*(const float4*)(e1+4), i1)
           + dot4(*(const float4*)(e1+8), i2) + dot4(*(const float4*)(e1+12),i3);
      ah0 += dot4(*(const float4*)m0,     o0) + dot4(*(const float4*)(m0+4), o1)
           + dot4(*(const float4*)(m0+8), o2) + dot4(*(const float4*)(m0+12),o3);
      ah1 += dot4(*(const float4*)m1,     o0) + dot4(*(const float4*)(m1+4), o1)
           + dot4(*(const float4*)(m1+8), o2) + dot4(*(const float4*)(m1+12),o3);
    }
    gis[0][tid] = ai0 + me_bih[tid];
    gis[1][tid] = ai1 + me_bih[tid];
    ghs[0][tid] = ah0 + me_bhh[tid];
    ghs[1][tid] = ah1 + me_bhh[tid];
    __syncthreads();
    if (tid < 256) {
      int r = tid >> 7, c = tid & 127;
      float mnew = gru_comb(gis[r][c], gis[r][c+H], gis[r][c+2*H],
                            ghs[r][c], ghs[r][c+H], ghs[r][c+2*H], ms[r][c]);
      mem[(size_t)(n0 + r)*H + c] = mnew;
    }
  }
}

// =====================================================================
// Decoder recurrence (gi fixed across steps)
// =====================================================================
__global__ __launch_bounds__(384) void k_decode(const float* __restrict__ embed,
    const float* __restrict__ qv, const float* __restrict__ mem,
    const float* __restrict__ an_Wih, const float* __restrict__ an_Whh,
    const float* __restrict__ an_bih, const float* __restrict__ an_bhh,
    float* __restrict__ h2d, int ND)
{
  __shared__ float hs[2][H], qs[2][H], e2[H], ghs[2][H3], gis[2][H3];
  int tid = threadIdx.x;
  int n0 = blockIdx.x * 2;
  if (tid < H) e2[tid] = embed[2*H + tid];
  if (tid < 256) {
    int r = tid >> 7, c = tid & 127;
    hs[r][c] = mem[(size_t)(n0 + r)*H + c];
    qs[r][c] = qv[(size_t)(n0 + r)*H + c];
  }
  __syncthreads();
  {
    const float* wp = an_Wih + (size_t)tid*(2*H);
    float se = 0.f, sq0 = 0.f, sq1 = 0.f;
    for (int kk = 0; kk < H; kk += 16) {
      float4 w0 = *(const float4*)(wp + kk);
      float4 w1 = *(const float4*)(wp + kk + 4);
      float4 w2 = *(const float4*)(wp + kk + 8);
      float4 w3 = *(const float4*)(wp + kk + 12);
      const float* ep = &e2[kk];
      se += dot4(*(const float4*)ep,     w0) + dot4(*(const float4*)(ep+4), w1)
          + dot4(*(const float4*)(ep+8), w2) + dot4(*(const float4*)(ep+12),w3);
      float4 u0 = *(const float4*)(wp + H + kk);
      float4 u1 = *(const float4*)(wp + H + kk + 4);
      float4 u2 = *(const float4*)(wp + H + kk + 8);
      float4 u3 = *(const float4*)(wp + H + kk + 12);
      const float* q0 = &qs[0][kk];
      const float* q1 = &qs[1][kk];
      sq0 += dot4(*(const float4*)q0,     u0) + dot4(*(const float4*)(q0+4), u1)
           + dot4(*(const float4*)(q0+8), u2) + dot4(*(const float4*)(q0+12),u3);
      sq1 += dot4(*(const float4*)q1,     u0) + dot4(*(const float4*)(q1+4), u1)
           + dot4(*(const float4*)(q1+8), u2) + dot4(*(const float4*)(q1+12),u3);
    }
    float b = an_bih[tid];
    gis[0][tid] = b + se + sq0;
    gis[1][tid] = b + se + sq1;
  }
  const float* whp = an_Whh + (size_t)tid*H;
  float bh = an_bhh[tid];
  for (int t = 0; t < ND; ++t) {
    float a0 = 0.f, a1 = 0.f;
    for (int kk = 0; kk < H; kk += 16) {
      float4 w0 = *(const float4*)(whp + kk);
      float4 w1 = *(const float4*)(whp + kk + 4);
      float4 w2 = *(const float4*)(whp + kk + 8);
      float4 w3 = *(const float4*)(whp + kk + 12);
      const float* h0p = &hs[0][kk];
      const float* h1p = &hs[1][kk];
      a0 += dot4(*(const float4*)h0p,     w0) + dot4(*(const float4*)(h0p+4), w1)
          + dot4(*(const float4*)(h0p+8), w2) + dot4(*(const float4*)(h0p+12),w3);
      a1 += dot4(*(const float4*)h1p,     w0) + dot4(*(const float4*)(h1p+4), w1)
          + dot4(*(const float4*)(h1p+8), w2) + dot4(*(const float4*)(h1p+12),w3);
    }
    ghs[0][tid] = a0 + bh;
    ghs[1][tid] = a1 + bh;
    __syncthreads();
    if (tid < 256) {
      int r = tid >> 7, c = tid & 127;
      float h2 = gru_comb(gis[r][c], gis[r][c+H], gis[r][c+2*H],
                          ghs[r][c], ghs[r][c+H], ghs[r][c+2*H], hs[r][c]);
      hs[r][c] = h2;
      h2d[((size_t)(n0 + r)*ND + t)*H + c] = h2;
    }
    __syncthreads();
  }
}

// per-row online max + sum(exp) -> lse
__global__ __launch_bounds__(256) void k_rowstat(const float* __restrict__ C, int V,
                                                 float* __restrict__ lse)
{
  __shared__ float mred[256], sred[256];
  int tid = threadIdx.x;
  const float* row = C + (size_t)blockIdx.x * V;
  float m = -3.402823466e38f, s = 0.f;
  for (int i = tid; i < V; i += 256) {
    float x = row[i];
    if (x > m) { s = s * expf(m - x) + 1.f; m = x; }
    else s += expf(x - m);
  }
  mred[tid] = m; sred[tid] = s;
  __syncthreads();
  for (int off = 128; off > 0; off >>= 1) {
    if (tid < off) {
      float m1 = mred[tid], s1 = sred[tid];
      float m2 = mred[tid + off], s2 = sred[tid + off];
      float M = fmaxf(m1, m2);
      sred[tid] = s1*expf(m1 - M) + s2*expf(m2 - M);
      mred[tid] = M;
    }
    __syncthreads();
  }
  if (tid == 0) lse[blockIdx.x] = mred[0] + logf(sred[0]);
}

__global__ __launch_bounds__(256) void k_sub(float* __restrict__ C,
    const float* __restrict__ lse, int V, long long tot4)
{
  long long i = (long long)blockIdx.x*256 + threadIdx.x;
  if (i >= tot4) return;
  float4* C4 = (float4*)C;
  float4 v = C4[i];
  int row = (int)((i*4) / V);
  float l = lse[row];
  v.x -= l; v.y -= l; v.z -= l; v.w -= l;
  C4[i] = v;
}

// =====================================================================
extern "C" void kernel_launch(void* const* d_in, const int* in_sizes, int n_in,
                              void* d_out, int out_size, void* d_ws, size_t ws_size,
                              hipStream_t stream) {
  const int*   facts     = (const int*)  d_in[0];
  const int*   fmask     = (const int*)  d_in[1];
  const int*   questions = (const int*)  d_in[2];
  const int*   qmask     = (const int*)  d_in[3];
  const float* embed     = (const float*)d_in[5];
  const float* ig_Wih    = (const float*)d_in[6];
  const float* ig_Whh    = (const float*)d_in[7];
  const float* ig_bih    = (const float*)d_in[8];
  const float* ig_bhh    = (const float*)d_in[9];
  const float* qg_Wih    = (const float*)d_in[10];
  const float* qg_Whh    = (const float*)d_in[11];
  const float* qg_bih    = (const float*)d_in[12];
  const float* qg_bhh    = (const float*)d_in[13];
  const float* at_Wih    = (const float*)d_in[14];
  const float* at_Whh    = (const float*)d_in[15];
  const float* at_bih    = (const float*)d_in[16];
  const float* at_bhh    = (const float*)d_in[17];
  const float* me_Wih    = (const float*)d_in[18];
  const float* me_Whh    = (const float*)d_in[19];
  const float* me_bih    = (const float*)d_in[20];
  const float* me_bhh    = (const float*)d_in[21];
  const float* an_Wih    = (const float*)d_in[22];
  const float* an_Whh    = (const float*)d_in[23];
  const float* an_bih    = (const float*)d_in[24];
  const float* an_bhh    = (const float*)d_in[25];
  const float* gate_W1   = (const float*)d_in[26];
  const float* gate_b1   = (const float*)d_in[27];
  const float* gate_W2   = (const float*)d_in[28];
  const float* gate_b2   = (const float*)d_in[29];
  const float* fc_W      = (const float*)d_in[30];
  const float* fc_b      = (const float*)d_in[31];
  (void)n_in; (void)ws_size;

  const int V  = in_sizes[5] / H;          // 50000
  const int ND = out_size / (NB * V);      // 8

  float* OUT = (float*)d_out;
  // d_out doubles as scratch for everything dead before the logits GEMM.
  size_t oP    = 0;
  size_t oEMBQ = (size_t)V * H3;
  size_t oQGI  = oEMBQ + (size_t)NB*TQ*H;
  size_t oGIAT = oQGI  + (size_t)NB*TQ*H3;
  size_t oU1   = oGIAT + (size_t)NF*H3;
  size_t oGATE = oU1   + (size_t)NF*H;
  float* P    = OUT + oP;
  float* EMBQ = OUT + oEMBQ;
  float* QGI  = OUT + oQGI;
  float* GIAT = OUT + oGIAT;
  float* U1b  = OUT + oU1;
  float* GATE = OUT + oGATE;

  float* encf = (float*)d_ws;              // NF*H
  float* qvec = encf + (size_t)NF*H;       // NB*H
  float* mem  = qvec + (size_t)NB*H;       // NB*H
  float* h2d  = mem  + (size_t)NB*H;       // NB*ND*H
  float* lse  = h2d  + (size_t)NB*ND*H;    // NB*ND

  // 1. fact-GRU input projection as vocab table: P = embed @ ig_Wih^T + ig_bih
  k_mgemm<<<dim3((V+63)/64, H3/128), 256, 0, stream>>>(embed, ig_Wih, ig_bih, P, V, H3);
  // 2-3. question embeddings + projection
  k_gather<<<NB*TQ, 128, 0, stream>>>(embed, questions, EMBQ);
  k_mgemm<<<dim3(NB*TQ/64, H3/128), 256, 0, stream>>>(EMBQ, qg_Wih, qg_bih, QGI, NB*TQ, H3);
  // 4. fact GRU scan (6400 seqs x 32 steps, MFMA)
  k_recgru<<<NF/16, 256, 0, stream>>>(P, facts, fmask, ig_Whh, ig_bhh, encf, TI);
  // 5. question GRU scan
  k_recgru<<<NB/16, 256, 0, stream>>>(QGI, nullptr, qmask, qg_Whh, qg_bhh, qvec, TQ);
  // 6. attention-GRU input projection for all facts
  k_mgemm<<<dim3(NF/64, H3/128), 256, 0, stream>>>(encf, at_Wih, at_bih, GIAT, NF, H3);
  // 7. m-independent gate half
  k_gatepre<<<NF/16, 128, 0, stream>>>(encf, qvec, gate_W1, gate_b1, U1b);
  // 8. memory = q
  k_copy<<<(NB*H+255)/256, 256, 0, stream>>>(qvec, mem, NB*H);
  // 9. episodes
  for (int e = 0; e < EPISODES; ++e) {
    k_gate<<<NF/16, 128, 0, stream>>>(encf, mem, gate_W1, gate_W2, gate_b2, U1b, GATE);
    k_episode<<<NB/2, 384, 0, stream>>>(GIAT, GATE, at_Whh, at_bhh,
                                        me_Wih, me_Whh, me_bih, me_bhh, mem);
  }
  // 10. decoder recurrence
  k_decode<<<NB/2, 384, 0, stream>>>(embed, qvec, mem, an_Wih, an_Whh, an_bih, an_bhh,
                                     h2d, ND);
  // 11. logits = h2 @ fc_W^T + fc_b (overwrites all of d_out)
  k_mgemm<<<dim3(NB*ND/64, (V+127)/128), 256, 0, stream>>>(h2d, fc_W, fc_b, OUT, NB*ND, V);
  // 12-13. log_softmax
  k_rowstat<<<NB*ND, 256, 0, stream>>>(OUT, V, lse);
  long long tot4 = (long long)NB*ND*V/4;
  k_sub<<<(unsigned)((tot4 + 255)/256), 256, 0, stream>>>(OUT, lse, V, tot4);
}

// Round 3
// 1179.908 us; speedup vs baseline: 2.5286x; 1.2405x over previous
//
#include <hip/hip_runtime.h>
#include <math.h>

// ---- model constants (match reference) ----
#define H   128
#define H3  384
#define TC  50
#define TI  32
#define TQ  32
#define NB  128
#define NF  (NB*TC)   // 6400 fact sequences
#define EPISODES 3

typedef short  bf16x8 __attribute__((ext_vector_type(8)));
typedef float  f32x4  __attribute__((ext_vector_type(4)));

__device__ __forceinline__ float dot4(float4 a, float4 b) {
  return a.x*b.x + a.y*b.y + a.z*b.z + a.w*b.w;
}
__device__ __forceinline__ float sigm(float x) { return 1.f/(1.f + __expf(-x)); }
__device__ __forceinline__ float tanh_f(float x) { return 1.f - 2.f/(1.f + __expf(2.f*x)); }
__device__ __forceinline__ float gru_comb(float ir, float iz, float inn,
                                          float hr, float hz, float hn, float h) {
  float r = sigm(ir + hr);
  float z = sigm(iz + hz);
  float n = tanh_f(inn + r*hn);
  return (1.f - z)*n + z*h;
}
__device__ __forceinline__ short f2bf(float x) {   // RNE f32 -> bf16
  union { float f; unsigned u; } v; v.f = x;
  unsigned r = v.u + 0x7fffu + ((v.u >> 16) & 1u);
  return (short)(r >> 16);
}
__device__ __forceinline__ float bf2f(short s) {
  union { unsigned u; float f; } v; v.u = ((unsigned)(unsigned short)s) << 16;
  return v.f;
}
__device__ __forceinline__ bf16x8 pack8(float4 lo, float4 hi) {
  bf16x8 o;
  o[0]=f2bf(lo.x); o[1]=f2bf(lo.y); o[2]=f2bf(lo.z); o[3]=f2bf(lo.w);
  o[4]=f2bf(hi.x); o[5]=f2bf(hi.y); o[6]=f2bf(hi.z); o[7]=f2bf(hi.w);
  return o;
}

// =====================================================================
// MFMA GEMM fp32-out: C[M,N] = A[M,128] @ B[N,128]^T + bias[N]
// =====================================================================
#define GM_LDA 136
__global__ __launch_bounds__(256) void k_mgemm(const float* __restrict__ A,
    const float* __restrict__ Bm, const float* __restrict__ bias,
    float* __restrict__ C, int M, int N)
{
  __shared__ __align__(16) short As[64][GM_LDA];
  __shared__ __align__(16) short Bs[128][GM_LDA];
  int tid = threadIdx.x;
  int lane = tid & 63, wave = tid >> 6;
  int bm = blockIdx.x, bn = blockIdx.y;
  #pragma unroll
  for (int i = 0; i < 4; ++i) {
    int ch = tid + i*256;
    int r = ch >> 4, e = (ch & 15)*8;
    int gr = bm*64 + r; if (gr > M-1) gr = M-1;
    const float* src = A + (size_t)gr*H + e;
    *(bf16x8*)&As[r][e] = pack8(*(const float4*)src, *(const float4*)(src+4));
  }
  #pragma unroll
  for (int i = 0; i < 8; ++i) {
    int ch = tid + i*256;
    int r = ch >> 4, e = (ch & 15)*8;
    int gn = bn*128 + r; if (gn > N-1) gn = N-1;
    const float* src = Bm + (size_t)gn*H + e;
    *(bf16x8*)&Bs[r][e] = pack8(*(const float4*)src, *(const float4*)(src+4));
  }
  __syncthreads();
  int q = lane >> 4, l15 = lane & 15;
  f32x4 acc[8];
  #pragma unroll
  for (int nt = 0; nt < 8; ++nt) { acc[nt][0]=0.f; acc[nt][1]=0.f; acc[nt][2]=0.f; acc[nt][3]=0.f; }
  int mrow = wave*16 + l15;
  #pragma unroll
  for (int kf = 0; kf < 4; ++kf) {
    bf16x8 a = *(bf16x8*)&As[mrow][q*8 + kf*32];
    #pragma unroll
    for (int nt = 0; nt < 8; ++nt) {
      bf16x8 b = *(bf16x8*)&Bs[nt*16 + l15][q*8 + kf*32];
      acc[nt] = __builtin_amdgcn_mfma_f32_16x16x32_bf16(a, b, acc[nt], 0, 0, 0);
    }
  }
  #pragma unroll
  for (int nt = 0; nt < 8; ++nt) {
    int col = bn*128 + nt*16 + l15;
    if (col < N) {
      float bv = bias[col];
      #pragma unroll
      for (int reg = 0; reg < 4; ++reg) {
        int row = bm*64 + wave*16 + q*4 + reg;
        if (row < M) C[(size_t)row*N + col] = acc[nt][reg] + bv;
      }
    }
  }
}

// =====================================================================
// MFMA GEMM bf16-out (for gi tables P / QGI / GIAT)
// =====================================================================
__global__ __launch_bounds__(256) void k_mgemm_bf16(const float* __restrict__ A,
    const float* __restrict__ Bm, const float* __restrict__ bias,
    short* __restrict__ C, int M, int N)
{
  __shared__ __align__(16) short As[64][GM_LDA];
  __shared__ __align__(16) short Bs[128][GM_LDA];
  int tid = threadIdx.x;
  int lane = tid & 63, wave = tid >> 6;
  int bm = blockIdx.x, bn = blockIdx.y;
  #pragma unroll
  for (int i = 0; i < 4; ++i) {
    int ch = tid + i*256;
    int r = ch >> 4, e = (ch & 15)*8;
    int gr = bm*64 + r; if (gr > M-1) gr = M-1;
    const float* src = A + (size_t)gr*H + e;
    *(bf16x8*)&As[r][e] = pack8(*(const float4*)src, *(const float4*)(src+4));
  }
  #pragma unroll
  for (int i = 0; i < 8; ++i) {
    int ch = tid + i*256;
    int r = ch >> 4, e = (ch & 15)*8;
    int gn = bn*128 + r; if (gn > N-1) gn = N-1;
    const float* src = Bm + (size_t)gn*H + e;
    *(bf16x8*)&Bs[r][e] = pack8(*(const float4*)src, *(const float4*)(src+4));
  }
  __syncthreads();
  int q = lane >> 4, l15 = lane & 15;
  f32x4 acc[8];
  #pragma unroll
  for (int nt = 0; nt < 8; ++nt) { acc[nt][0]=0.f; acc[nt][1]=0.f; acc[nt][2]=0.f; acc[nt][3]=0.f; }
  int mrow = wave*16 + l15;
  #pragma unroll
  for (int kf = 0; kf < 4; ++kf) {
    bf16x8 a = *(bf16x8*)&As[mrow][q*8 + kf*32];
    #pragma unroll
    for (int nt = 0; nt < 8; ++nt) {
      bf16x8 b = *(bf16x8*)&Bs[nt*16 + l15][q*8 + kf*32];
      acc[nt] = __builtin_amdgcn_mfma_f32_16x16x32_bf16(a, b, acc[nt], 0, 0, 0);
    }
  }
  #pragma unroll
  for (int nt = 0; nt < 8; ++nt) {
    int col = bn*128 + nt*16 + l15;
    if (col < N) {
      float bv = bias[col];
      #pragma unroll
      for (int reg = 0; reg < 4; ++reg) {
        int row = bm*64 + wave*16 + q*4 + reg;
        if (row < M) C[(size_t)row*N + col] = f2bf(acc[nt][reg] + bv);
      }
    }
  }
}

// gather embedding rows for question tokens
__global__ __launch_bounds__(128) void k_gather(const float* __restrict__ embed,
    const int* __restrict__ toks, float* __restrict__ dst)
{
  int b = blockIdx.x;
  int t = toks[b];
  dst[(size_t)b*H + threadIdx.x] = embed[(size_t)t*H + threadIdx.x];
}

__global__ __launch_bounds__(256) void k_copy(const float* __restrict__ src,
    float* __restrict__ dst, int n)
{
  int i = blockIdx.x*256 + threadIdx.x;
  if (i < n) dst[i] = src[i];
}

// =====================================================================
// Fused GRU scan v2. 16 seqs/block, 512 threads (8 waves), 1 barrier/step.
// - wave w owns col-tiles {w, w+8, w+16}: cols c=16w+l15 (+128, +256) ->
//   each lane's accs are exactly (gh_r, gh_z, gh_n) for its own (row, c):
//   GRU elementwise fully in registers, h state register-resident.
// - gi table is bf16; gi(t+1) staged into double-buffered LDS with wide
//   coalesced b128 loads (12 wave-loads/block-step).
// - h bf16 scatter into double-buffered LDS A-operand buffer.
// =====================================================================
#define GI_STR 392   // shorts; 784B row stride: 16B-aligned, q-quads 8 banks apart
__global__ __launch_bounds__(512) void k_recgru2(
    const short* __restrict__ GI, const int* __restrict__ toks,
    const int* __restrict__ masks,
    const float* __restrict__ Whh, const float* __restrict__ bhh,
    float* __restrict__ enc_out, int steps)
{
  __shared__ __align__(16) short hsb[2][16][136];
  __shared__ __align__(16) short gib[2][16][GI_STR];
  __shared__ int ltoks[16*TI];
  __shared__ int enc_step_s[16];
  int tid = threadIdx.x;
  int lane = tid & 63, wave = tid >> 6;
  int q = lane >> 4, l15 = lane & 15;
  int seq0 = blockIdx.x * 16;

  for (int i = tid; i < 2*16*136; i += 512) ((short*)hsb)[i] = 0;
  if (toks) for (int i = tid; i < 16*steps; i += 512)
    ltoks[i] = toks[(size_t)seq0*steps + i];
  if (tid < 16) {
    int fl = 0;
    for (int i = 0; i < steps; ++i) fl += (masks[(size_t)(seq0+tid)*steps + i] == 0);
    int et = fl - 1; if (et < 0) et = 0; if (et >= steps) et = steps-1;
    enc_step_s[tid] = et;
  }
  // weight fragments: wave w owns cols n = 16w + 128i + l15 (i=0..2)
  bf16x8 wfrag[3][4];
  #pragma unroll
  for (int i = 0; i < 3; ++i) {
    int n = 16*wave + 128*i + l15;
    const float* wr = Whh + (size_t)n*H + q*8;
    #pragma unroll
    for (int kf = 0; kf < 4; ++kf)
      wfrag[i][kf] = pack8(*(const float4*)(wr + kf*32), *(const float4*)(wr + kf*32 + 4));
  }
  int c = 16*wave + l15;
  float bh0 = bhh[c], bh1 = bhh[c+H], bh2 = bhh[c+2*H];
  // gather chunk mapping: 768 chunks of 16B (16 rows x 48)
  int ch0 = tid, ch1 = tid + 512;
  int r0 = ch0/48, o0 = ch0 - r0*48;
  int r1 = ch1/48, o1 = ch1 - r1*48;
  __syncthreads();                       // ltoks / enc_step ready
  int es[4];
  #pragma unroll
  for (int reg = 0; reg < 4; ++reg) es[reg] = enc_step_s[q*4 + reg];

  // stage gi(0)
  {
    size_t row0 = toks ? (size_t)ltoks[r0*steps] : ((size_t)(seq0 + r0)*steps);
    *(bf16x8*)&gib[0][r0][o0*8] = *((const bf16x8*)(GI + row0*H3) + o0);
    if (tid < 256) {
      size_t row1 = toks ? (size_t)ltoks[r1*steps] : ((size_t)(seq0 + r1)*steps);
      *(bf16x8*)&gib[0][r1][o1*8] = *((const bf16x8*)(GI + row1*H3) + o1);
    }
  }
  __syncthreads();

  float hreg[4] = {0.f, 0.f, 0.f, 0.f};
  for (int t = 0; t < steps; ++t) {
    // prefetch gi(t+1) -> regs (latency hidden under the whole step)
    bf16x8 pf0, pf1;
    bool havepf = (t + 1 < steps);
    if (havepf) {
      size_t row0 = toks ? (size_t)ltoks[r0*steps + t + 1]
                         : ((size_t)(seq0 + r0)*steps + t + 1);
      pf0 = *((const bf16x8*)(GI + row0*H3) + o0);
      if (tid < 256) {
        size_t row1 = toks ? (size_t)ltoks[r1*steps + t + 1]
                           : ((size_t)(seq0 + r1)*steps + t + 1);
        pf1 = *((const bf16x8*)(GI + row1*H3) + o1);
      }
    }
    // gh = h @ Whh^T (this wave's 3 col families)
    f32x4 acc[3];
    #pragma unroll
    for (int i = 0; i < 3; ++i) { acc[i][0]=0.f; acc[i][1]=0.f; acc[i][2]=0.f; acc[i][3]=0.f; }
    #pragma unroll
    for (int kf = 0; kf < 4; ++kf) {
      bf16x8 a = *(bf16x8*)&hsb[t & 1][l15][kf*32 + q*8];
      #pragma unroll
      for (int i = 0; i < 3; ++i)
        acc[i] = __builtin_amdgcn_mfma_f32_16x16x32_bf16(a, wfrag[i][kf], acc[i], 0, 0, 0);
    }
    // in-register GRU elementwise (acc row = q*4+reg, col = c)
    #pragma unroll
    for (int reg = 0; reg < 4; ++reg) {
      int row = q*4 + reg;
      float gr = bf2f(gib[t & 1][row][c]);
      float gz = bf2f(gib[t & 1][row][c + 128]);
      float gn = bf2f(gib[t & 1][row][c + 256]);
      float hnew = gru_comb(gr, gz, gn,
                            acc[0][reg] + bh0, acc[1][reg] + bh1, acc[2][reg] + bh2,
                            hreg[reg]);
      hreg[reg] = hnew;
      hsb[(t + 1) & 1][row][c] = f2bf(hnew);
      if (t == es[reg]) enc_out[(size_t)(seq0 + row)*H + c] = hnew;
    }
    // commit prefetched gi(t+1)
    if (havepf) {
      *(bf16x8*)&gib[(t + 1) & 1][r0][o0*8] = pf0;
      if (tid < 256) *(bf16x8*)&gib[(t + 1) & 1][r1][o1*8] = pf1;
    }
    __syncthreads();
  }
}

// =====================================================================
// U1[nt][c] = (f*q)@W1a^T + |f-q|@W1c^T + b1
// =====================================================================
__global__ __launch_bounds__(128) void k_gatepre(const float* __restrict__ encf,
    const float* __restrict__ qv, const float* __restrict__ W1,
    const float* __restrict__ b1, float* __restrict__ U1)
{
  __shared__ float us[16][H], vs[16][H];
  int tid = threadIdx.x;
  int nt0 = blockIdx.x * 16;
  for (int i = tid; i < 16*H; i += 128) {
    int r = i >> 7, k = i & 127;
    int nt = nt0 + r, n = nt / TC;
    float f = encf[(size_t)nt*H + k];
    float q = qv[(size_t)n*H + k];
    us[r][k] = f*q;
    vs[r][k] = fabsf(f - q);
  }
  __syncthreads();
  int c = tid;
  float acc[16] = {};
  const float* wa = W1 + (size_t)c*(4*H);
  const float* wc = wa + 2*H;
  for (int kk = 0; kk < H; kk += 16) {
    float4 a0 = *(const float4*)(wa + kk);
    float4 a1 = *(const float4*)(wa + kk + 4);
    float4 a2 = *(const float4*)(wa + kk + 8);
    float4 a3 = *(const float4*)(wa + kk + 12);
    float4 c0 = *(const float4*)(wc + kk);
    float4 c1 = *(const float4*)(wc + kk + 4);
    float4 c2 = *(const float4*)(wc + kk + 8);
    float4 c3 = *(const float4*)(wc + kk + 12);
    #pragma unroll
    for (int r = 0; r < 16; ++r) {
      const float* up = &us[r][kk];
      const float* vp = &vs[r][kk];
      acc[r] += dot4(*(const float4*)up,     a0) + dot4(*(const float4*)(up+4), a1)
              + dot4(*(const float4*)(up+8), a2) + dot4(*(const float4*)(up+12),a3)
              + dot4(*(const float4*)vp,     c0) + dot4(*(const float4*)(vp+4), c1)
              + dot4(*(const float4*)(vp+8), c2) + dot4(*(const float4*)(vp+12),c3);
    }
  }
  float bb = b1[c];
  #pragma unroll
  for (int r = 0; r < 16; ++r) U1[(size_t)(nt0 + r)*H + c] = acc[r] + bb;
}

// =====================================================================
// Per-episode gates (batched over all 50 steps)
// =====================================================================
__global__ __launch_bounds__(128) void k_gate(const float* __restrict__ encf,
    const float* __restrict__ mem, const float* __restrict__ W1,
    const float* __restrict__ W2, const float* __restrict__ b2,
    const float* __restrict__ U1, float* __restrict__ gate)
{
  __shared__ float us[16][H], vs[16][H], hid[16][H], parts[16][8];
  int tid = threadIdx.x;
  int nt0 = blockIdx.x * 16;
  for (int i = tid; i < 16*H; i += 128) {
    int r = i >> 7, k = i & 127;
    int nt = nt0 + r, n = nt / TC;
    float f = encf[(size_t)nt*H + k];
    float m = mem[(size_t)n*H + k];
    us[r][k] = f*m;
    vs[r][k] = fabsf(f - m);
  }
  __syncthreads();
  int c = tid;
  float acc[16];
  #pragma unroll
  for (int r = 0; r < 16; ++r) acc[r] = U1[(size_t)(nt0 + r)*H + c];
  const float* wb = W1 + (size_t)c*(4*H) + H;
  const float* wd = W1 + (size_t)c*(4*H) + 3*H;
  for (int kk = 0; kk < H; kk += 16) {
    float4 a0 = *(const float4*)(wb + kk);
    float4 a1 = *(const float4*)(wb + kk + 4);
    float4 a2 = *(const float4*)(wb + kk + 8);
    float4 a3 = *(const float4*)(wb + kk + 12);
    float4 c0 = *(const float4*)(wd + kk);
    float4 c1 = *(const float4*)(wd + kk + 4);
    float4 c2 = *(const float4*)(wd + kk + 8);
    float4 c3 = *(const float4*)(wd + kk + 12);
    #pragma unroll
    for (int r = 0; r < 16; ++r) {
      const float* up = &us[r][kk];
      const float* vp = &vs[r][kk];
      acc[r] += dot4(*(const float4*)up,     a0) + dot4(*(const float4*)(up+4), a1)
              + dot4(*(const float4*)(up+8), a2) + dot4(*(const float4*)(up+12),a3)
              + dot4(*(const float4*)vp,     c0) + dot4(*(const float4*)(vp+4), c1)
              + dot4(*(const float4*)(vp+8), c2) + dot4(*(const float4*)(vp+12),c3);
    }
  }
  #pragma unroll
  for (int r = 0; r < 16; ++r) hid[r][c] = tanh_f(acc[r]);
  __syncthreads();
  {
    int r = tid >> 3, i = tid & 7;
    float p = 0.f;
    for (int k = i*16; k < i*16 + 16; ++k) p += hid[r][k]*W2[k];
    parts[r][i] = p;
  }
  __syncthreads();
  if (tid < 16) {
    float s = b2[0];
    #pragma unroll
    for (int i = 0; i < 8; ++i) s += parts[tid][i];
    gate[nt0 + tid] = sigm(s);
  }
}

// =====================================================================
// Episode v2: 16 batch rows/block (8 blocks), recgru2-style MFMA scan with
// at_Whh register-resident; fused me-GRU memory update at the end.
// =====================================================================
__global__ __launch_bounds__(512) void k_episode2(
    const short* __restrict__ GIat, const float* __restrict__ gate,
    const float* __restrict__ at_Whh, const float* __restrict__ at_bhh,
    const float* __restrict__ me_Wih, const float* __restrict__ me_Whh,
    const float* __restrict__ me_bih, const float* __restrict__ me_bhh,
    float* __restrict__ mem)
{
  __shared__ __align__(16) short hsb[2][16][136];
  __shared__ __align__(16) short msb[16][136];
  __shared__ __align__(16) short gib[2][16][GI_STR];
  int tid = threadIdx.x;
  int lane = tid & 63, wave = tid >> 6;
  int q = lane >> 4, l15 = lane & 15;
  int n0 = blockIdx.x * 16;

  for (int i = tid; i < 2*16*136; i += 512) ((short*)hsb)[i] = 0;
  for (int i = tid; i < 16*H; i += 512) {
    int r = i >> 7, cc = i & 127;
    msb[r][cc] = f2bf(mem[(size_t)(n0 + r)*H + cc]);
  }
  bf16x8 wfrag[3][4];
  #pragma unroll
  for (int i = 0; i < 3; ++i) {
    int n = 16*wave + 128*i + l15;
    const float* wr = at_Whh + (size_t)n*H + q*8;
    #pragma unroll
    for (int kf = 0; kf < 4; ++kf)
      wfrag[i][kf] = pack8(*(const float4*)(wr + kf*32), *(const float4*)(wr + kf*32 + 4));
  }
  int c = 16*wave + l15;
  float bh0 = at_bhh[c], bh1 = at_bhh[c+H], bh2 = at_bhh[c+2*H];
  int ch0 = tid, ch1 = tid + 512;
  int r0 = ch0/48, o0 = ch0 - r0*48;
  int r1 = ch1/48, o1 = ch1 - r1*48;
  __syncthreads();

  // stage gi(0): rowid = (n0+row)*TC
  *(bf16x8*)&gib[0][r0][o0*8] = *((const bf16x8*)(GIat + (size_t)(n0 + r0)*TC*H3) + o0);
  if (tid < 256)
    *(bf16x8*)&gib[0][r1][o1*8] = *((const bf16x8*)(GIat + (size_t)(n0 + r1)*TC*H3) + o1);
  __syncthreads();

  float hreg[4] = {0.f, 0.f, 0.f, 0.f};
  for (int t = 0; t < TC; ++t) {
    bf16x8 pf0, pf1;
    bool havepf = (t + 1 < TC);
    if (havepf) {
      pf0 = *((const bf16x8*)(GIat + ((size_t)(n0 + r0)*TC + t + 1)*H3) + o0);
      if (tid < 256)
        pf1 = *((const bf16x8*)(GIat + ((size_t)(n0 + r1)*TC + t + 1)*H3) + o1);
    }
    f32x4 acc[3];
    #pragma unroll
    for (int i = 0; i < 3; ++i) { acc[i][0]=0.f; acc[i][1]=0.f; acc[i][2]=0.f; acc[i][3]=0.f; }
    #pragma unroll
    for (int kf = 0; kf < 4; ++kf) {
      bf16x8 a = *(bf16x8*)&hsb[t & 1][l15][kf*32 + q*8];
      #pragma unroll
      for (int i = 0; i < 3; ++i)
        acc[i] = __builtin_amdgcn_mfma_f32_16x16x32_bf16(a, wfrag[i][kf], acc[i], 0, 0, 0);
    }
    #pragma unroll
    for (int reg = 0; reg < 4; ++reg) {
      int row = q*4 + reg;
      float g  = gate[(size_t)(n0 + row)*TC + t];
      float gr = bf2f(gib[t & 1][row][c]);
      float gz = bf2f(gib[t & 1][row][c + 128]);
      float gn = bf2f(gib[t & 1][row][c + 256]);
      float h2 = gru_comb(gr, gz, gn,
                          acc[0][reg] + bh0, acc[1][reg] + bh1, acc[2][reg] + bh2,
                          hreg[reg]);
      float hnew = g*h2 + (1.f - g)*hreg[reg];
      hreg[reg] = hnew;
      hsb[(t + 1) & 1][row][c] = f2bf(hnew);
    }
    if (havepf) {
      *(bf16x8*)&gib[(t + 1) & 1][r0][o0*8] = pf0;
      if (tid < 256) *(bf16x8*)&gib[(t + 1) & 1][r1][o1*8] = pf1;
    }
    __syncthreads();
  }
  // memory = GRUcell(e = h(TC) [in hsb[TC&1] = hsb[0]], m) with me_* weights
  f32x4 gi_acc[3], gh_acc[3];
  #pragma unroll
  for (int i = 0; i < 3; ++i) {
    gi_acc[i][0]=0.f; gi_acc[i][1]=0.f; gi_acc[i][2]=0.f; gi_acc[i][3]=0.f;
    gh_acc[i][0]=0.f; gh_acc[i][1]=0.f; gh_acc[i][2]=0.f; gh_acc[i][3]=0.f;
  }
  #pragma unroll
  for (int i = 0; i < 3; ++i) {        // reuse wfrag storage: me_Wih
    int n = 16*wave + 128*i + l15;
    const float* wr = me_Wih + (size_t)n*H + q*8;
    #pragma unroll
    for (int kf = 0; kf < 4; ++kf)
      wfrag[i][kf] = pack8(*(const float4*)(wr + kf*32), *(const float4*)(wr + kf*32 + 4));
  }
  #pragma unroll
  for (int kf = 0; kf < 4; ++kf) {
    bf16x8 a = *(bf16x8*)&hsb[TC & 1][l15][kf*32 + q*8];
    #pragma unroll
    for (int i = 0; i < 3; ++i)
      gi_acc[i] = __builtin_amdgcn_mfma_f32_16x16x32_bf16(a, wfrag[i][kf], gi_acc[i], 0, 0, 0);
  }
  #pragma unroll
  for (int i = 0; i < 3; ++i) {        // me_Whh
    int n = 16*wave + 128*i + l15;
    const float* wr = me_Whh + (size_t)n*H + q*8;
    #pragma unroll
    for (int kf = 0; kf < 4; ++kf)
      wfrag[i][kf] = pack8(*(const float4*)(wr + kf*32), *(const float4*)(wr + kf*32 + 4));
  }
  #pragma unroll
  for (int kf = 0; kf < 4; ++kf) {
    bf16x8 a = *(bf16x8*)&msb[l15][kf*32 + q*8];
    #pragma unroll
    for (int i = 0; i < 3; ++i)
      gh_acc[i] = __builtin_amdgcn_mfma_f32_16x16x32_bf16(a, wfrag[i][kf], gh_acc[i], 0, 0, 0);
  }
  float bi0 = me_bih[c], bi1 = me_bih[c+H], bi2 = me_bih[c+2*H];
  float bo0 = me_bhh[c], bo1 = me_bhh[c+H], bo2 = me_bhh[c+2*H];
  #pragma unroll
  for (int reg = 0; reg < 4; ++reg) {
    int row = q*4 + reg;
    float m = mem[(size_t)(n0 + row)*H + c];
    float mnew = gru_comb(gi_acc[0][reg] + bi0, gi_acc[1][reg] + bi1, gi_acc[2][reg] + bi2,
                          gh_acc[0][reg] + bo0, gh_acc[1][reg] + bo1, gh_acc[2][reg] + bo2, m);
    mem[(size_t)(n0 + row)*H + c] = mnew;
  }
}

// =====================================================================
// Decoder recurrence (gi fixed across steps)
// =====================================================================
__global__ __launch_bounds__(384) void k_decode(const float* __restrict__ embed,
    const float* __restrict__ qv, const float* __restrict__ mem,
    const float* __restrict__ an_Wih, const float* __restrict__ an_Whh,
    const float* __restrict__ an_bih, const float* __restrict__ an_bhh,
    float* __restrict__ h2d, int ND)
{
  __shared__ float hs[2][H], qs[2][H], e2[H], ghs[2][H3], gis[2][H3];
  int tid = threadIdx.x;
  int n0 = blockIdx.x * 2;
  if (tid < H) e2[tid] = embed[2*H + tid];
  if (tid < 256) {
    int r = tid >> 7, c = tid & 127;
    hs[r][c] = mem[(size_t)(n0 + r)*H + c];
    qs[r][c] = qv[(size_t)(n0 + r)*H + c];
  }
  __syncthreads();
  {
    const float* wp = an_Wih + (size_t)tid*(2*H);
    float se = 0.f, sq0 = 0.f, sq1 = 0.f;
    for (int kk = 0; kk < H; kk += 16) {
      float4 w0 = *(const float4*)(wp + kk);
      float4 w1 = *(const float4*)(wp + kk + 4);
      float4 w2 = *(const float4*)(wp + kk + 8);
      float4 w3 = *(const float4*)(wp + kk + 12);
      const float* ep = &e2[kk];
      se += dot4(*(const float4*)ep,     w0) + dot4(*(const float4*)(ep+4), w1)
          + dot4(*(const float4*)(ep+8), w2) + dot4(*(const float4*)(ep+12),w3);
      float4 u0 = *(const float4*)(wp + H + kk);
      float4 u1 = *(const float4*)(wp + H + kk + 4);
      float4 u2 = *(const float4*)(wp + H + kk + 8);
      float4 u3 = *(const float4*)(wp + H + kk + 12);
      const float* q0 = &qs[0][kk];
      const float* q1 = &qs[1][kk];
      sq0 += dot4(*(const float4*)q0,     u0) + dot4(*(const float4*)(q0+4), u1)
           + dot4(*(const float4*)(q0+8), u2) + dot4(*(const float4*)(q0+12),u3);
      sq1 += dot4(*(const float4*)q1,     u0) + dot4(*(const float4*)(q1+4), u1)
           + dot4(*(const float4*)(q1+8), u2) + dot4(*(const float4*)(q1+12),u3);
    }
    float b = an_bih[tid];
    gis[0][tid] = b + se + sq0;
    gis[1][tid] = b + se + sq1;
  }
  const float* whp = an_Whh + (size_t)tid*H;
  float bh = an_bhh[tid];
  for (int t = 0; t < ND; ++t) {
    float a0 = 0.f, a1 = 0.f;
    for (int kk = 0; kk < H; kk += 16) {
      float4 w0 = *(const float4*)(whp + kk);
      float4 w1 = *(const float4*)(whp + kk + 4);
      float4 w2 = *(const float4*)(whp + kk + 8);
      float4 w3 = *(const float4*)(whp + kk + 12);
      const float* h0p = &hs[0][kk];
      const float* h1p = &hs[1][kk];
      a0 += dot4(*(const float4*)h0p,     w0) + dot4(*(const float4*)(h0p+4), w1)
          + dot4(*(const float4*)(h0p+8), w2) + dot4(*(const float4*)(h0p+12),w3);
      a1 += dot4(*(const float4*)h1p,     w0) + dot4(*(const float4*)(h1p+4), w1)
          + dot4(*(const float4*)(h1p+8), w2) + dot4(*(const float4*)(h1p+12),w3);
    }
    ghs[0][tid] = a0 + bh;
    ghs[1][tid] = a1 + bh;
    __syncthreads();
    if (tid < 256) {
      int r = tid >> 7, c = tid & 127;
      float h2 = gru_comb(gis[r][c], gis[r][c+H], gis[r][c+2*H],
                          ghs[r][c], ghs[r][c+H], ghs[r][c+2*H], hs[r][c]);
      hs[r][c] = h2;
      h2d[((size_t)(n0 + r)*ND + t)*H + c] = h2;
    }
    __syncthreads();
  }
}

// per-row online max + sum(exp) -> lse
__global__ __launch_bounds__(256) void k_rowstat(const float* __restrict__ C, int V,
                                                 float* __restrict__ lse)
{
  __shared__ float mred[256], sred[256];
  int tid = threadIdx.x;
  const float* row = C + (size_t)blockIdx.x * V;
  float m = -3.402823466e38f, s = 0.f;
  for (int i = tid; i < V; i += 256) {
    float x = row[i];
    if (x > m) { s = s * __expf(m - x) + 1.f; m = x; }
    else s += __expf(x - m);
  }
  mred[tid] = m; sred[tid] = s;
  __syncthreads();
  for (int off = 128; off > 0; off >>= 1) {
    if (tid < off) {
      float m1 = mred[tid], s1 = sred[tid];
      float m2 = mred[tid + off], s2 = sred[tid + off];
      float M = fmaxf(m1, m2);
      sred[tid] = s1*__expf(m1 - M) + s2*__expf(m2 - M);
      mred[tid] = M;
    }
    __syncthreads();
  }
  if (tid == 0) lse[blockIdx.x] = mred[0] + logf(sred[0]);
}

__global__ __launch_bounds__(256) void k_sub(float* __restrict__ C,
    const float* __restrict__ lse, int V, long long tot4)
{
  long long i = (long long)blockIdx.x*256 + threadIdx.x;
  if (i >= tot4) return;
  float4* C4 = (float4*)C;
  float4 v = C4[i];
  int row = (int)((i*4) / V);
  float l = lse[row];
  v.x -= l; v.y -= l; v.z -= l; v.w -= l;
  C4[i] = v;
}

// =====================================================================
extern "C" void kernel_launch(void* const* d_in, const int* in_sizes, int n_in,
                              void* d_out, int out_size, void* d_ws, size_t ws_size,
                              hipStream_t stream) {
  const int*   facts     = (const int*)  d_in[0];
  const int*   fmask     = (const int*)  d_in[1];
  const int*   questions = (const int*)  d_in[2];
  const int*   qmask     = (const int*)  d_in[3];
  const float* embed     = (const float*)d_in[5];
  const float* ig_Wih    = (const float*)d_in[6];
  const float* ig_Whh    = (const float*)d_in[7];
  const float* ig_bih    = (const float*)d_in[8];
  const float* ig_bhh    = (const float*)d_in[9];
  const float* qg_Wih    = (const float*)d_in[10];
  const float* qg_Whh    = (const float*)d_in[11];
  const float* qg_bih    = (const float*)d_in[12];
  const float* qg_bhh    = (const float*)d_in[13];
  const float* at_Wih    = (const float*)d_in[14];
  const float* at_Whh    = (const float*)d_in[15];
  const float* at_bih    = (const float*)d_in[16];
  const float* at_bhh    = (const float*)d_in[17];
  const float* me_Wih    = (const float*)d_in[18];
  const float* me_Whh    = (const float*)d_in[19];
  const float* me_bih    = (const float*)d_in[20];
  const float* me_bhh    = (const float*)d_in[21];
  const float* an_Wih    = (const float*)d_in[22];
  const float* an_Whh    = (const float*)d_in[23];
  const float* an_bih    = (const float*)d_in[24];
  const float* an_bhh    = (const float*)d_in[25];
  const float* gate_W1   = (const float*)d_in[26];
  const float* gate_b1   = (const float*)d_in[27];
  const float* gate_W2   = (const float*)d_in[28];
  const float* gate_b2   = (const float*)d_in[29];
  const float* fc_W      = (const float*)d_in[30];
  const float* fc_b      = (const float*)d_in[31];
  (void)n_in; (void)ws_size;

  const int V  = in_sizes[5] / H;          // 50000
  const int ND = out_size / (NB * V);      // 8

  float* OUT = (float*)d_out;
  // d_out doubles as scratch for everything dead before the logits GEMM.
  // gi tables are bf16 now (half the floats).
  size_t oP    = 0;                                // P: V*384 bf16 = V*192 floats
  size_t oEMBQ = (size_t)V * 192;
  size_t oQGI  = oEMBQ + (size_t)NB*TQ*H;          // QGI: NB*TQ*384 bf16
  size_t oGIAT = oQGI  + (size_t)NB*TQ*192;        // GIAT: NF*384 bf16
  size_t oU1   = oGIAT + (size_t)NF*192;
  size_t oGATE = oU1   + (size_t)NF*H;
  short* Psh    = (short*)(OUT + oP);
  float* EMBQ   = OUT + oEMBQ;
  short* QGIsh  = (short*)(OUT + oQGI);
  short* GIATsh = (short*)(OUT + oGIAT);
  float* U1b    = OUT + oU1;
  float* GATE   = OUT + oGATE;

  float* encf = (float*)d_ws;              // NF*H
  float* qvec = encf + (size_t)NF*H;       // NB*H
  float* mem  = qvec + (size_t)NB*H;       // NB*H
  float* h2d  = mem  + (size_t)NB*H;       // NB*ND*H
  float* lse  = h2d  + (size_t)NB*ND*H;    // NB*ND

  // 1. fact-GRU input projection as bf16 vocab table
  k_mgemm_bf16<<<dim3((V+63)/64, H3/128), 256, 0, stream>>>(embed, ig_Wih, ig_bih, Psh, V, H3);
  // 2-3. question embeddings + projection (bf16 table)
  k_gather<<<NB*TQ, 128, 0, stream>>>(embed, questions, EMBQ);
  k_mgemm_bf16<<<dim3(NB*TQ/64, H3/128), 256, 0, stream>>>(EMBQ, qg_Wih, qg_bih, QGIsh, NB*TQ, H3);
  // 4. fact GRU scan (6400 seqs x 32 steps)
  k_recgru2<<<NF/16, 512, 0, stream>>>(Psh, facts, fmask, ig_Whh, ig_bhh, encf, TI);
  // 5. question GRU scan
  k_recgru2<<<NB/16, 512, 0, stream>>>(QGIsh, nullptr, qmask, qg_Whh, qg_bhh, qvec, TQ);
  // 6. attention-GRU input projection (bf16 table)
  k_mgemm_bf16<<<dim3(NF/64, H3/128), 256, 0, stream>>>(encf, at_Wih, at_bih, GIATsh, NF, H3);
  // 7. m-independent gate half
  k_gatepre<<<NF/16, 128, 0, stream>>>(encf, qvec, gate_W1, gate_b1, U1b);
  // 8. memory = q
  k_copy<<<(NB*H+255)/256, 256, 0, stream>>>(qvec, mem, NB*H);
  // 9. episodes
  for (int e = 0; e < EPISODES; ++e) {
    k_gate<<<NF/16, 128, 0, stream>>>(encf, mem, gate_W1, gate_W2, gate_b2, U1b, GATE);
    k_episode2<<<NB/16, 512, 0, stream>>>(GIATsh, GATE, at_Whh, at_bhh,
                                          me_Wih, me_Whh, me_bih, me_bhh, mem);
  }
  // 10. decoder recurrence
  k_decode<<<NB/2, 384, 0, stream>>>(embed, qvec, mem, an_Wih, an_Whh, an_bih, an_bhh,
                                     h2d, ND);
  // 11. logits = h2 @ fc_W^T + fc_b (overwrites all of d_out)
  k_mgemm<<<dim3(NB*ND/64, (V+127)/128), 256, 0, stream>>>(h2d, fc_W, fc_b, OUT, NB*ND, V);
  // 12-13. log_softmax
  k_rowstat<<<NB*ND, 256, 0, stream>>>(OUT, V, lse);
  long long tot4 = (long long)NB*ND*V/4;
  k_sub<<<(unsigned)((tot4 + 255)/256), 256, 0, stream>>>(OUT, lse, V, tot4);
}

// Round 4
// 1001.300 us; speedup vs baseline: 2.9797x; 1.1784x over previous
//
#include <hip/hip_runtime.h>
#include <math.h>

// ---- model constants (match reference) ----
#define H   128
#define H3  384
#define TC  50
#define TI  32
#define TQ  32
#define NB  128
#define NF  (NB*TC)   // 6400 fact sequences
#define EPISODES 3
#define LSLICE 25     // V-slices for lse pass (25 x 2048 >= 50000)

typedef short  bf16x8 __attribute__((ext_vector_type(8)));
typedef float  f32x4  __attribute__((ext_vector_type(4)));

__device__ __forceinline__ float dot4(float4 a, float4 b) {
  return a.x*b.x + a.y*b.y + a.z*b.z + a.w*b.w;
}
__device__ __forceinline__ float sigm(float x) { return 1.f/(1.f + __expf(-x)); }
__device__ __forceinline__ float tanh_f(float x) { return 1.f - 2.f/(1.f + __expf(2.f*x)); }
__device__ __forceinline__ float gru_comb(float ir, float iz, float inn,
                                          float hr, float hz, float hn, float h) {
  float r = sigm(ir + hr);
  float z = sigm(iz + hz);
  float n = tanh_f(inn + r*hn);
  return (1.f - z)*n + z*h;
}
__device__ __forceinline__ short f2bf(float x) {   // RNE f32 -> bf16
  union { float f; unsigned u; } v; v.f = x;
  unsigned r = v.u + 0x7fffu + ((v.u >> 16) & 1u);
  return (short)(r >> 16);
}
__device__ __forceinline__ float bf2f(short s) {
  union { unsigned u; float f; } v; v.u = ((unsigned)(unsigned short)s) << 16;
  return v.f;
}
__device__ __forceinline__ bf16x8 pack8(float4 lo, float4 hi) {
  bf16x8 o;
  o[0]=f2bf(lo.x); o[1]=f2bf(lo.y); o[2]=f2bf(lo.z); o[3]=f2bf(lo.w);
  o[4]=f2bf(hi.x); o[5]=f2bf(hi.y); o[6]=f2bf(hi.z); o[7]=f2bf(hi.w);
  return o;
}

// =====================================================================
// MFMA GEMM bf16-out (gi tables P / QGI / GIAT), coalesced short8 stores
// via LDS restage. N must be a multiple of 128 here (N=384 always).
// =====================================================================
__global__ __launch_bounds__(256) void k_mgemm_bf16(const float* __restrict__ A,
    const float* __restrict__ Bm, const float* __restrict__ bias,
    short* __restrict__ C, int M, int N)
{
  __shared__ __align__(16) short As[64][136];
  __shared__ __align__(16) short Bs[128][136];
  int tid = threadIdx.x;
  int lane = tid & 63, wave = tid >> 6;
  int bm = blockIdx.x, bn = blockIdx.y;
  #pragma unroll
  for (int i = 0; i < 4; ++i) {
    int ch = tid + i*256;
    int r = ch >> 4, e = (ch & 15)*8;
    int gr = bm*64 + r; if (gr > M-1) gr = M-1;
    const float* src = A + (size_t)gr*H + e;
    *(bf16x8*)&As[r][e] = pack8(*(const float4*)src, *(const float4*)(src+4));
  }
  #pragma unroll
  for (int i = 0; i < 8; ++i) {
    int ch = tid + i*256;
    int r = ch >> 4, e = (ch & 15)*8;
    int gn = bn*128 + r; if (gn > N-1) gn = N-1;
    const float* src = Bm + (size_t)gn*H + e;
    *(bf16x8*)&Bs[r][e] = pack8(*(const float4*)src, *(const float4*)(src+4));
  }
  __syncthreads();
  int q = lane >> 4, l15 = lane & 15;
  f32x4 acc[8];
  #pragma unroll
  for (int nt = 0; nt < 8; ++nt) { acc[nt][0]=0.f; acc[nt][1]=0.f; acc[nt][2]=0.f; acc[nt][3]=0.f; }
  int mrow = wave*16 + l15;
  #pragma unroll
  for (int kf = 0; kf < 4; ++kf) {
    bf16x8 a = *(bf16x8*)&As[mrow][q*8 + kf*32];
    #pragma unroll
    for (int nt = 0; nt < 8; ++nt) {
      bf16x8 b = *(bf16x8*)&Bs[nt*16 + l15][q*8 + kf*32];
      acc[nt] = __builtin_amdgcn_mfma_f32_16x16x32_bf16(a, b, acc[nt], 0, 0, 0);
    }
  }
  __syncthreads();               // done reading Bs; reuse rows 0..63 as C tile
  #pragma unroll
  for (int nt = 0; nt < 8; ++nt) {
    int col = nt*16 + l15;
    float bv = bias[bn*128 + col];
    #pragma unroll
    for (int reg = 0; reg < 4; ++reg)
      Bs[wave*16 + q*4 + reg][col] = f2bf(acc[nt][reg] + bv);
  }
  __syncthreads();
  #pragma unroll
  for (int i = 0; i < 4; ++i) {   // 1024 short8 chunks (64 rows x 16)
    int idx = tid + i*256;
    int r = idx >> 4, e = (idx & 15)*8;
    int gr = bm*64 + r;
    if (gr < M) *(bf16x8*)(C + (size_t)gr*N + bn*128 + e) = *(bf16x8*)&Bs[r][e];
  }
}

// gather embedding rows for question tokens
__global__ __launch_bounds__(128) void k_gather(const float* __restrict__ embed,
    const int* __restrict__ toks, float* __restrict__ dst)
{
  int b = blockIdx.x;
  int t = toks[b];
  dst[(size_t)b*H + threadIdx.x] = embed[(size_t)t*H + threadIdx.x];
}

__global__ __launch_bounds__(256) void k_copy(const float* __restrict__ src,
    float* __restrict__ dst, int n)
{
  int i = blockIdx.x*256 + threadIdx.x;
  if (i < n) dst[i] = src[i];
}

// =====================================================================
// Fused GRU scan v2. 16 seqs/block, 512 threads (8 waves), 1 barrier/step.
// =====================================================================
#define GI_STR 392
__global__ __launch_bounds__(512) void k_recgru2(
    const short* __restrict__ GI, const int* __restrict__ toks,
    const int* __restrict__ masks,
    const float* __restrict__ Whh, const float* __restrict__ bhh,
    float* __restrict__ enc_out, int steps)
{
  __shared__ __align__(16) short hsb[2][16][136];
  __shared__ __align__(16) short gib[2][16][GI_STR];
  __shared__ int ltoks[16*TI];
  __shared__ int enc_step_s[16];
  int tid = threadIdx.x;
  int lane = tid & 63, wave = tid >> 6;
  int q = lane >> 4, l15 = lane & 15;
  int seq0 = blockIdx.x * 16;

  for (int i = tid; i < 2*16*136; i += 512) ((short*)hsb)[i] = 0;
  if (toks) for (int i = tid; i < 16*steps; i += 512)
    ltoks[i] = toks[(size_t)seq0*steps + i];
  if (tid < 16) {
    int fl = 0;
    for (int i = 0; i < steps; ++i) fl += (masks[(size_t)(seq0+tid)*steps + i] == 0);
    int et = fl - 1; if (et < 0) et = 0; if (et >= steps) et = steps-1;
    enc_step_s[tid] = et;
  }
  bf16x8 wfrag[3][4];
  #pragma unroll
  for (int i = 0; i < 3; ++i) {
    int n = 16*wave + 128*i + l15;
    const float* wr = Whh + (size_t)n*H + q*8;
    #pragma unroll
    for (int kf = 0; kf < 4; ++kf)
      wfrag[i][kf] = pack8(*(const float4*)(wr + kf*32), *(const float4*)(wr + kf*32 + 4));
  }
  int c = 16*wave + l15;
  float bh0 = bhh[c], bh1 = bhh[c+H], bh2 = bhh[c+2*H];
  int ch0 = tid, ch1 = tid + 512;
  int r0 = ch0/48, o0 = ch0 - r0*48;
  int r1 = ch1/48, o1 = ch1 - r1*48;
  __syncthreads();
  int es[4];
  #pragma unroll
  for (int reg = 0; reg < 4; ++reg) es[reg] = enc_step_s[q*4 + reg];

  {
    size_t row0 = toks ? (size_t)ltoks[r0*steps] : ((size_t)(seq0 + r0)*steps);
    *(bf16x8*)&gib[0][r0][o0*8] = *((const bf16x8*)(GI + row0*H3) + o0);
    if (tid < 256) {
      size_t row1 = toks ? (size_t)ltoks[r1*steps] : ((size_t)(seq0 + r1)*steps);
      *(bf16x8*)&gib[0][r1][o1*8] = *((const bf16x8*)(GI + row1*H3) + o1);
    }
  }
  __syncthreads();

  float hreg[4] = {0.f, 0.f, 0.f, 0.f};
  for (int t = 0; t < steps; ++t) {
    bf16x8 pf0, pf1;
    bool havepf = (t + 1 < steps);
    if (havepf) {
      size_t row0 = toks ? (size_t)ltoks[r0*steps + t + 1]
                         : ((size_t)(seq0 + r0)*steps + t + 1);
      pf0 = *((const bf16x8*)(GI + row0*H3) + o0);
      if (tid < 256) {
        size_t row1 = toks ? (size_t)ltoks[r1*steps + t + 1]
                           : ((size_t)(seq0 + r1)*steps + t + 1);
        pf1 = *((const bf16x8*)(GI + row1*H3) + o1);
      }
    }
    f32x4 acc[3];
    #pragma unroll
    for (int i = 0; i < 3; ++i) { acc[i][0]=0.f; acc[i][1]=0.f; acc[i][2]=0.f; acc[i][3]=0.f; }
    #pragma unroll
    for (int kf = 0; kf < 4; ++kf) {
      bf16x8 a = *(bf16x8*)&hsb[t & 1][l15][kf*32 + q*8];
      #pragma unroll
      for (int i = 0; i < 3; ++i)
        acc[i] = __builtin_amdgcn_mfma_f32_16x16x32_bf16(a, wfrag[i][kf], acc[i], 0, 0, 0);
    }
    #pragma unroll
    for (int reg = 0; reg < 4; ++reg) {
      int row = q*4 + reg;
      float gr = bf2f(gib[t & 1][row][c]);
      float gz = bf2f(gib[t & 1][row][c + 128]);
      float gn = bf2f(gib[t & 1][row][c + 256]);
      float hnew = gru_comb(gr, gz, gn,
                            acc[0][reg] + bh0, acc[1][reg] + bh1, acc[2][reg] + bh2,
                            hreg[reg]);
      hreg[reg] = hnew;
      hsb[(t + 1) & 1][row][c] = f2bf(hnew);
      if (t == es[reg]) enc_out[(size_t)(seq0 + row)*H + c] = hnew;
    }
    if (havepf) {
      *(bf16x8*)&gib[(t + 1) & 1][r0][o0*8] = pf0;
      if (tid < 256) *(bf16x8*)&gib[(t + 1) & 1][r1][o1*8] = pf1;
    }
    __syncthreads();
  }
}

// =====================================================================
// U1[nt][c] = (f*q)@W1a^T + |f-q|@W1c^T + b1
// =====================================================================
__global__ __launch_bounds__(128) void k_gatepre(const float* __restrict__ encf,
    const float* __restrict__ qv, const float* __restrict__ W1,
    const float* __restrict__ b1, float* __restrict__ U1)
{
  __shared__ float us[16][H], vs[16][H];
  int tid = threadIdx.x;
  int nt0 = blockIdx.x * 16;
  for (int i = tid; i < 16*H; i += 128) {
    int r = i >> 7, k = i & 127;
    int nt = nt0 + r, n = nt / TC;
    float f = encf[(size_t)nt*H + k];
    float q = qv[(size_t)n*H + k];
    us[r][k] = f*q;
    vs[r][k] = fabsf(f - q);
  }
  __syncthreads();
  int c = tid;
  float acc[16] = {};
  const float* wa = W1 + (size_t)c*(4*H);
  const float* wc = wa + 2*H;
  for (int kk = 0; kk < H; kk += 16) {
    float4 a0 = *(const float4*)(wa + kk);
    float4 a1 = *(const float4*)(wa + kk + 4);
    float4 a2 = *(const float4*)(wa + kk + 8);
    float4 a3 = *(const float4*)(wa + kk + 12);
    float4 c0 = *(const float4*)(wc + kk);
    float4 c1 = *(const float4*)(wc + kk + 4);
    float4 c2 = *(const float4*)(wc + kk + 8);
    float4 c3 = *(const float4*)(wc + kk + 12);
    #pragma unroll
    for (int r = 0; r < 16; ++r) {
      const float* up = &us[r][kk];
      const float* vp = &vs[r][kk];
      acc[r] += dot4(*(const float4*)up,     a0) + dot4(*(const float4*)(up+4), a1)
              + dot4(*(const float4*)(up+8), a2) + dot4(*(const float4*)(up+12),a3)
              + dot4(*(const float4*)vp,     c0) + dot4(*(const float4*)(vp+4), c1)
              + dot4(*(const float4*)(vp+8), c2) + dot4(*(const float4*)(vp+12),c3);
    }
  }
  float bb = b1[c];
  #pragma unroll
  for (int r = 0; r < 16; ++r) U1[(size_t)(nt0 + r)*H + c] = acc[r] + bb;
}

// =====================================================================
// Per-episode gates (batched over all 50 steps)
// =====================================================================
__global__ __launch_bounds__(128) void k_gate(const float* __restrict__ encf,
    const float* __restrict__ mem, const float* __restrict__ W1,
    const float* __restrict__ W2, const float* __restrict__ b2,
    const float* __restrict__ U1, float* __restrict__ gate)
{
  __shared__ float us[16][H], vs[16][H], hid[16][H], parts[16][8];
  int tid = threadIdx.x;
  int nt0 = blockIdx.x * 16;
  for (int i = tid; i < 16*H; i += 128) {
    int r = i >> 7, k = i & 127;
    int nt = nt0 + r, n = nt / TC;
    float f = encf[(size_t)nt*H + k];
    float m = mem[(size_t)n*H + k];
    us[r][k] = f*m;
    vs[r][k] = fabsf(f - m);
  }
  __syncthreads();
  int c = tid;
  float acc[16];
  #pragma unroll
  for (int r = 0; r < 16; ++r) acc[r] = U1[(size_t)(nt0 + r)*H + c];
  const float* wb = W1 + (size_t)c*(4*H) + H;
  const float* wd = W1 + (size_t)c*(4*H) + 3*H;
  for (int kk = 0; kk < H; kk += 16) {
    float4 a0 = *(const float4*)(wb + kk);
    float4 a1 = *(const float4*)(wb + kk + 4);
    float4 a2 = *(const float4*)(wb + kk + 8);
    float4 a3 = *(const float4*)(wb + kk + 12);
    float4 c0 = *(const float4*)(wd + kk);
    float4 c1 = *(const float4*)(wd + kk + 4);
    float4 c2 = *(const float4*)(wd + kk + 8);
    float4 c3 = *(const float4*)(wd + kk + 12);
    #pragma unroll
    for (int r = 0; r < 16; ++r) {
      const float* up = &us[r][kk];
      const float* vp = &vs[r][kk];
      acc[r] += dot4(*(const float4*)up,     a0) + dot4(*(const float4*)(up+4), a1)
              + dot4(*(const float4*)(up+8), a2) + dot4(*(const float4*)(up+12),a3)
              + dot4(*(const float4*)vp,     c0) + dot4(*(const float4*)(vp+4), c1)
              + dot4(*(const float4*)(vp+8), c2) + dot4(*(const float4*)(vp+12),c3);
    }
  }
  #pragma unroll
  for (int r = 0; r < 16; ++r) hid[r][c] = tanh_f(acc[r]);
  __syncthreads();
  {
    int r = tid >> 3, i = tid & 7;
    float p = 0.f;
    for (int k = i*16; k < i*16 + 16; ++k) p += hid[r][k]*W2[k];
    parts[r][i] = p;
  }
  __syncthreads();
  if (tid < 16) {
    float s = b2[0];
    #pragma unroll
    for (int i = 0; i < 8; ++i) s += parts[tid][i];
    gate[nt0 + tid] = sigm(s);
  }
}

// =====================================================================
// Episode v2: 16 batch rows/block, MFMA scan, fused me-GRU memory update
// =====================================================================
__global__ __launch_bounds__(512) void k_episode2(
    const short* __restrict__ GIat, const float* __restrict__ gate,
    const float* __restrict__ at_Whh, const float* __restrict__ at_bhh,
    const float* __restrict__ me_Wih, const float* __restrict__ me_Whh,
    const float* __restrict__ me_bih, const float* __restrict__ me_bhh,
    float* __restrict__ mem)
{
  __shared__ __align__(16) short hsb[2][16][136];
  __shared__ __align__(16) short msb[16][136];
  __shared__ __align__(16) short gib[2][16][GI_STR];
  int tid = threadIdx.x;
  int lane = tid & 63, wave = tid >> 6;
  int q = lane >> 4, l15 = lane & 15;
  int n0 = blockIdx.x * 16;

  for (int i = tid; i < 2*16*136; i += 512) ((short*)hsb)[i] = 0;
  for (int i = tid; i < 16*H; i += 512) {
    int r = i >> 7, cc = i & 127;
    msb[r][cc] = f2bf(mem[(size_t)(n0 + r)*H + cc]);
  }
  bf16x8 wfrag[3][4];
  #pragma unroll
  for (int i = 0; i < 3; ++i) {
    int n = 16*wave + 128*i + l15;
    const float* wr = at_Whh + (size_t)n*H + q*8;
    #pragma unroll
    for (int kf = 0; kf < 4; ++kf)
      wfrag[i][kf] = pack8(*(const float4*)(wr + kf*32), *(const float4*)(wr + kf*32 + 4));
  }
  int c = 16*wave + l15;
  float bh0 = at_bhh[c], bh1 = at_bhh[c+H], bh2 = at_bhh[c+2*H];
  int ch0 = tid, ch1 = tid + 512;
  int r0 = ch0/48, o0 = ch0 - r0*48;
  int r1 = ch1/48, o1 = ch1 - r1*48;
  __syncthreads();

  *(bf16x8*)&gib[0][r0][o0*8] = *((const bf16x8*)(GIat + (size_t)(n0 + r0)*TC*H3) + o0);
  if (tid < 256)
    *(bf16x8*)&gib[0][r1][o1*8] = *((const bf16x8*)(GIat + (size_t)(n0 + r1)*TC*H3) + o1);
  __syncthreads();

  float hreg[4] = {0.f, 0.f, 0.f, 0.f};
  for (int t = 0; t < TC; ++t) {
    bf16x8 pf0, pf1;
    bool havepf = (t + 1 < TC);
    if (havepf) {
      pf0 = *((const bf16x8*)(GIat + ((size_t)(n0 + r0)*TC + t + 1)*H3) + o0);
      if (tid < 256)
        pf1 = *((const bf16x8*)(GIat + ((size_t)(n0 + r1)*TC + t + 1)*H3) + o1);
    }
    f32x4 acc[3];
    #pragma unroll
    for (int i = 0; i < 3; ++i) { acc[i][0]=0.f; acc[i][1]=0.f; acc[i][2]=0.f; acc[i][3]=0.f; }
    #pragma unroll
    for (int kf = 0; kf < 4; ++kf) {
      bf16x8 a = *(bf16x8*)&hsb[t & 1][l15][kf*32 + q*8];
      #pragma unroll
      for (int i = 0; i < 3; ++i)
        acc[i] = __builtin_amdgcn_mfma_f32_16x16x32_bf16(a, wfrag[i][kf], acc[i], 0, 0, 0);
    }
    #pragma unroll
    for (int reg = 0; reg < 4; ++reg) {
      int row = q*4 + reg;
      float g  = gate[(size_t)(n0 + row)*TC + t];
      float gr = bf2f(gib[t & 1][row][c]);
      float gz = bf2f(gib[t & 1][row][c + 128]);
      float gn = bf2f(gib[t & 1][row][c + 256]);
      float h2 = gru_comb(gr, gz, gn,
                          acc[0][reg] + bh0, acc[1][reg] + bh1, acc[2][reg] + bh2,
                          hreg[reg]);
      float hnew = g*h2 + (1.f - g)*hreg[reg];
      hreg[reg] = hnew;
      hsb[(t + 1) & 1][row][c] = f2bf(hnew);
    }
    if (havepf) {
      *(bf16x8*)&gib[(t + 1) & 1][r0][o0*8] = pf0;
      if (tid < 256) *(bf16x8*)&gib[(t + 1) & 1][r1][o1*8] = pf1;
    }
    __syncthreads();
  }
  f32x4 gi_acc[3], gh_acc[3];
  #pragma unroll
  for (int i = 0; i < 3; ++i) {
    gi_acc[i][0]=0.f; gi_acc[i][1]=0.f; gi_acc[i][2]=0.f; gi_acc[i][3]=0.f;
    gh_acc[i][0]=0.f; gh_acc[i][1]=0.f; gh_acc[i][2]=0.f; gh_acc[i][3]=0.f;
  }
  #pragma unroll
  for (int i = 0; i < 3; ++i) {
    int n = 16*wave + 128*i + l15;
    const float* wr = me_Wih + (size_t)n*H + q*8;
    #pragma unroll
    for (int kf = 0; kf < 4; ++kf)
      wfrag[i][kf] = pack8(*(const float4*)(wr + kf*32), *(const float4*)(wr + kf*32 + 4));
  }
  #pragma unroll
  for (int kf = 0; kf < 4; ++kf) {
    bf16x8 a = *(bf16x8*)&hsb[TC & 1][l15][kf*32 + q*8];
    #pragma unroll
    for (int i = 0; i < 3; ++i)
      gi_acc[i] = __builtin_amdgcn_mfma_f32_16x16x32_bf16(a, wfrag[i][kf], gi_acc[i], 0, 0, 0);
  }
  #pragma unroll
  for (int i = 0; i < 3; ++i) {
    int n = 16*wave + 128*i + l15;
    const float* wr = me_Whh + (size_t)n*H + q*8;
    #pragma unroll
    for (int kf = 0; kf < 4; ++kf)
      wfrag[i][kf] = pack8(*(const float4*)(wr + kf*32), *(const float4*)(wr + kf*32 + 4));
  }
  #pragma unroll
  for (int kf = 0; kf < 4; ++kf) {
    bf16x8 a = *(bf16x8*)&msb[l15][kf*32 + q*8];
    #pragma unroll
    for (int i = 0; i < 3; ++i)
      gh_acc[i] = __builtin_amdgcn_mfma_f32_16x16x32_bf16(a, wfrag[i][kf], gh_acc[i], 0, 0, 0);
  }
  float bi0 = me_bih[c], bi1 = me_bih[c+H], bi2 = me_bih[c+2*H];
  float bo0 = me_bhh[c], bo1 = me_bhh[c+H], bo2 = me_bhh[c+2*H];
  #pragma unroll
  for (int reg = 0; reg < 4; ++reg) {
    int row = q*4 + reg;
    float m = mem[(size_t)(n0 + row)*H + c];
    float mnew = gru_comb(gi_acc[0][reg] + bi0, gi_acc[1][reg] + bi1, gi_acc[2][reg] + bi2,
                          gh_acc[0][reg] + bo0, gh_acc[1][reg] + bo1, gh_acc[2][reg] + bo2, m);
    mem[(size_t)(n0 + row)*H + c] = mnew;
  }
}

// =====================================================================
// Decoder recurrence (gi fixed across steps)
// =====================================================================
__global__ __launch_bounds__(384) void k_decode(const float* __restrict__ embed,
    const float* __restrict__ qv, const float* __restrict__ mem,
    const float* __restrict__ an_Wih, const float* __restrict__ an_Whh,
    const float* __restrict__ an_bih, const float* __restrict__ an_bhh,
    float* __restrict__ h2d, int ND)
{
  __shared__ float hs[2][H], qs[2][H], e2[H], ghs[2][H3], gis[2][H3];
  int tid = threadIdx.x;
  int n0 = blockIdx.x * 2;
  if (tid < H) e2[tid] = embed[2*H + tid];
  if (tid < 256) {
    int r = tid >> 7, c = tid & 127;
    hs[r][c] = mem[(size_t)(n0 + r)*H + c];
    qs[r][c] = qv[(size_t)(n0 + r)*H + c];
  }
  __syncthreads();
  {
    const float* wp = an_Wih + (size_t)tid*(2*H);
    float se = 0.f, sq0 = 0.f, sq1 = 0.f;
    for (int kk = 0; kk < H; kk += 16) {
      float4 w0 = *(const float4*)(wp + kk);
      float4 w1 = *(const float4*)(wp + kk + 4);
      float4 w2 = *(const float4*)(wp + kk + 8);
      float4 w3 = *(const float4*)(wp + kk + 12);
      const float* ep = &e2[kk];
      se += dot4(*(const float4*)ep,     w0) + dot4(*(const float4*)(ep+4), w1)
          + dot4(*(const float4*)(ep+8), w2) + dot4(*(const float4*)(ep+12),w3);
      float4 u0 = *(const float4*)(wp + H + kk);
      float4 u1 = *(const float4*)(wp + H + kk + 4);
      float4 u2 = *(const float4*)(wp + H + kk + 8);
      float4 u3 = *(const float4*)(wp + H + kk + 12);
      const float* q0 = &qs[0][kk];
      const float* q1 = &qs[1][kk];
      sq0 += dot4(*(const float4*)q0,     u0) + dot4(*(const float4*)(q0+4), u1)
           + dot4(*(const float4*)(q0+8), u2) + dot4(*(const float4*)(q0+12),u3);
      sq1 += dot4(*(const float4*)q1,     u0) + dot4(*(const float4*)(q1+4), u1)
           + dot4(*(const float4*)(q1+8), u2) + dot4(*(const float4*)(q1+12),u3);
    }
    float b = an_bih[tid];
    gis[0][tid] = b + se + sq0;
    gis[1][tid] = b + se + sq1;
  }
  const float* whp = an_Whh + (size_t)tid*H;
  float bh = an_bhh[tid];
  for (int t = 0; t < ND; ++t) {
    float a0 = 0.f, a1 = 0.f;
    for (int kk = 0; kk < H; kk += 16) {
      float4 w0 = *(const float4*)(whp + kk);
      float4 w1 = *(const float4*)(whp + kk + 4);
      float4 w2 = *(const float4*)(whp + kk + 8);
      float4 w3 = *(const float4*)(whp + kk + 12);
      const float* h0p = &hs[0][kk];
      const float* h1p = &hs[1][kk];
      a0 += dot4(*(const float4*)h0p,     w0) + dot4(*(const float4*)(h0p+4), w1)
          + dot4(*(const float4*)(h0p+8), w2) + dot4(*(const float4*)(h0p+12),w3);
      a1 += dot4(*(const float4*)h1p,     w0) + dot4(*(const float4*)(h1p+4), w1)
          + dot4(*(const float4*)(h1p+8), w2) + dot4(*(const float4*)(h1p+12),w3);
    }
    ghs[0][tid] = a0 + bh;
    ghs[1][tid] = a1 + bh;
    __syncthreads();
    if (tid < 256) {
      int r = tid >> 7, c = tid & 127;
      float h2 = gru_comb(gis[r][c], gis[r][c+H], gis[r][c+2*H],
                          ghs[r][c], ghs[r][c+H], ghs[r][c+2*H], hs[r][c]);
      hs[r][c] = h2;
      h2d[((size_t)(n0 + r)*ND + t)*H + c] = h2;
    }
    __syncthreads();
  }
}

// =====================================================================
// Logits pass 1: GEMM in registers, online (max, sum-exp) per row over a
// 2048-col slice -> partials[row][slice]. No logits written.
// =====================================================================
__global__ __launch_bounds__(256) void k_lpass1(const float* __restrict__ A,
    const float* __restrict__ Bm, const float* __restrict__ bias,
    float2* __restrict__ partials, int M, int N)
{
  __shared__ __align__(16) short As[64][136];
  __shared__ __align__(16) short Bs[128][136];
  int tid = threadIdx.x;
  int lane = tid & 63, wave = tid >> 6;
  int q = lane >> 4, l15 = lane & 15;
  int bm = blockIdx.x, sl = blockIdx.y;
  #pragma unroll
  for (int i = 0; i < 4; ++i) {
    int ch = tid + i*256;
    int r = ch >> 4, e = (ch & 15)*8;
    int gr = bm*64 + r; if (gr > M-1) gr = M-1;
    const float* src = A + (size_t)gr*H + e;
    *(bf16x8*)&As[r][e] = pack8(*(const float4*)src, *(const float4*)(src+4));
  }
  int mrow = wave*16 + l15;
  float m[4] = {-3.4e38f, -3.4e38f, -3.4e38f, -3.4e38f};
  float s[4] = {0.f, 0.f, 0.f, 0.f};
  for (int chn = 0; chn < 16; ++chn) {
    int c0 = sl*2048 + chn*128;
    #pragma unroll
    for (int i = 0; i < 8; ++i) {
      int ch = tid + i*256;
      int r = ch >> 4, e = (ch & 15)*8;
      int gn = c0 + r; if (gn > N-1) gn = N-1;
      const float* src = Bm + (size_t)gn*H + e;
      *(bf16x8*)&Bs[r][e] = pack8(*(const float4*)src, *(const float4*)(src+4));
    }
    __syncthreads();
    f32x4 acc[8];
    #pragma unroll
    for (int nt = 0; nt < 8; ++nt) { acc[nt][0]=0.f; acc[nt][1]=0.f; acc[nt][2]=0.f; acc[nt][3]=0.f; }
    #pragma unroll
    for (int kf = 0; kf < 4; ++kf) {
      bf16x8 a = *(bf16x8*)&As[mrow][q*8 + kf*32];
      #pragma unroll
      for (int nt = 0; nt < 8; ++nt) {
        bf16x8 b = *(bf16x8*)&Bs[nt*16 + l15][q*8 + kf*32];
        acc[nt] = __builtin_amdgcn_mfma_f32_16x16x32_bf16(a, b, acc[nt], 0, 0, 0);
      }
    }
    __syncthreads();
    float bv[8];
    #pragma unroll
    for (int nt = 0; nt < 8; ++nt) {
      int col = c0 + nt*16 + l15;
      bv[nt] = (col < N) ? bias[col] : 0.f;
    }
    #pragma unroll
    for (int reg = 0; reg < 4; ++reg) {
      float xs[8], cm = -3.4e38f;
      #pragma unroll
      for (int nt = 0; nt < 8; ++nt) {
        int col = c0 + nt*16 + l15;
        float x = (col < N) ? (acc[nt][reg] + bv[nt]) : -3.4e38f;
        xs[nt] = x; cm = fmaxf(cm, x);
      }
      float nm = fmaxf(m[reg], cm);
      float ss = s[reg] * __expf(m[reg] - nm);
      #pragma unroll
      for (int nt = 0; nt < 8; ++nt) ss += __expf(xs[nt] - nm);
      m[reg] = nm; s[reg] = ss;
    }
  }
  // reduce across the 16 lanes (l15) sharing each row
  #pragma unroll
  for (int off = 1; off < 16; off <<= 1) {
    #pragma unroll
    for (int reg = 0; reg < 4; ++reg) {
      float mo = __shfl_xor(m[reg], off);
      float so = __shfl_xor(s[reg], off);
      float nm = fmaxf(m[reg], mo);
      s[reg] = s[reg]*__expf(m[reg] - nm) + so*__expf(mo - nm);
      m[reg] = nm;
    }
  }
  if (l15 == 0) {
    #pragma unroll
    for (int reg = 0; reg < 4; ++reg) {
      int row = bm*64 + wave*16 + q*4 + reg;
      if (row < M) partials[(size_t)row*LSLICE + sl] = make_float2(m[reg], s[reg]);
    }
  }
}

// combine per-slice partials -> lse per row
__global__ __launch_bounds__(256) void k_lse(const float2* __restrict__ partials,
                                             float* __restrict__ lse, int M)
{
  int row = blockIdx.x*256 + threadIdx.x;
  if (row >= M) return;
  float m = -3.4e38f, s = 0.f;
  for (int i = 0; i < LSLICE; ++i) {
    float2 p = partials[(size_t)row*LSLICE + i];
    float nm = fmaxf(m, p.x);
    s = s*__expf(m - nm) + p.y*__expf(p.x - nm);
    m = nm;
  }
  lse[row] = m + logf(s);
}

// =====================================================================
// Logits pass 2: recompute GEMM, apply +bias - lse[row], coalesced float4
// stores via LDS restage.
// =====================================================================
__global__ __launch_bounds__(256) void k_lpass2(const float* __restrict__ A,
    const float* __restrict__ Bm, const float* __restrict__ bias,
    const float* __restrict__ lse, float* __restrict__ C, int M, int N)
{
  __shared__ __align__(16) short As[64][136];
  __shared__ __align__(16) short Bs[128][136];
  int tid = threadIdx.x;
  int lane = tid & 63, wave = tid >> 6;
  int q = lane >> 4, l15 = lane & 15;
  int bm = blockIdx.x, bn = blockIdx.y;
  #pragma unroll
  for (int i = 0; i < 4; ++i) {
    int ch = tid + i*256;
    int r = ch >> 4, e = (ch & 15)*8;
    int gr = bm*64 + r; if (gr > M-1) gr = M-1;
    const float* src = A + (size_t)gr*H + e;
    *(bf16x8*)&As[r][e] = pack8(*(const float4*)src, *(const float4*)(src+4));
  }
  #pragma unroll
  for (int i = 0; i < 8; ++i) {
    int ch = tid + i*256;
    int r = ch >> 4, e = (ch & 15)*8;
    int gn = bn*128 + r; if (gn > N-1) gn = N-1;
    const float* src = Bm + (size_t)gn*H + e;
    *(bf16x8*)&Bs[r][e] = pack8(*(const float4*)src, *(const float4*)(src+4));
  }
  __syncthreads();
  f32x4 acc[8];
  #pragma unroll
  for (int nt = 0; nt < 8; ++nt) { acc[nt][0]=0.f; acc[nt][1]=0.f; acc[nt][2]=0.f; acc[nt][3]=0.f; }
  int mrow = wave*16 + l15;
  #pragma unroll
  for (int kf = 0; kf < 4; ++kf) {
    bf16x8 a = *(bf16x8*)&As[mrow][q*8 + kf*32];
    #pragma unroll
    for (int nt = 0; nt < 8; ++nt) {
      bf16x8 b = *(bf16x8*)&Bs[nt*16 + l15][q*8 + kf*32];
      acc[nt] = __builtin_amdgcn_mfma_f32_16x16x32_bf16(a, b, acc[nt], 0, 0, 0);
    }
  }
  __syncthreads();                 // Bs free -> reuse as fp32 C tile [64][132]
  float (*Cs)[132] = (float(*)[132])&Bs[0][0];
  float lrow[4];
  #pragma unroll
  for (int reg = 0; reg < 4; ++reg) {
    int row = bm*64 + wave*16 + q*4 + reg;
    lrow[reg] = lse[row < M ? row : M-1];
  }
  #pragma unroll
  for (int nt = 0; nt < 8; ++nt) {
    int col = nt*16 + l15;
    int gcol = bn*128 + col;
    float bv = (gcol < N) ? bias[gcol] : 0.f;
    #pragma unroll
    for (int reg = 0; reg < 4; ++reg)
      Cs[wave*16 + q*4 + reg][col] = acc[nt][reg] + bv - lrow[reg];
  }
  __syncthreads();
  #pragma unroll
  for (int i = 0; i < 8; ++i) {   // 2048 float4 chunks (64 rows x 32)
    int idx = tid + i*256;
    int r = idx >> 5, c4 = (idx & 31)*4;
    int gr = bm*64 + r;
    int gc = bn*128 + c4;
    if (gr < M && gc + 3 < N)
      *(float4*)(C + (size_t)gr*N + gc) = *(float4*)&Cs[r][c4];
    else if (gr < M) {
      #pragma unroll
      for (int j = 0; j < 4; ++j)
        if (gc + j < N) C[(size_t)gr*N + gc + j] = Cs[r][c4 + j];
    }
  }
}

// =====================================================================
extern "C" void kernel_launch(void* const* d_in, const int* in_sizes, int n_in,
                              void* d_out, int out_size, void* d_ws, size_t ws_size,
                              hipStream_t stream) {
  const int*   facts     = (const int*)  d_in[0];
  const int*   fmask     = (const int*)  d_in[1];
  const int*   questions = (const int*)  d_in[2];
  const int*   qmask     = (const int*)  d_in[3];
  const float* embed     = (const float*)d_in[5];
  const float* ig_Wih    = (const float*)d_in[6];
  const float* ig_Whh    = (const float*)d_in[7];
  const float* ig_bih    = (const float*)d_in[8];
  const float* ig_bhh    = (const float*)d_in[9];
  const float* qg_Wih    = (const float*)d_in[10];
  const float* qg_Whh    = (const float*)d_in[11];
  const float* qg_bih    = (const float*)d_in[12];
  const float* qg_bhh    = (const float*)d_in[13];
  const float* at_Wih    = (const float*)d_in[14];
  const float* at_Whh    = (const float*)d_in[15];
  const float* at_bih    = (const float*)d_in[16];
  const float* at_bhh    = (const float*)d_in[17];
  const float* me_Wih    = (const float*)d_in[18];
  const float* me_Whh    = (const float*)d_in[19];
  const float* me_bih    = (const float*)d_in[20];
  const float* me_bhh    = (const float*)d_in[21];
  const float* an_Wih    = (const float*)d_in[22];
  const float* an_Whh    = (const float*)d_in[23];
  const float* an_bih    = (const float*)d_in[24];
  const float* an_bhh    = (const float*)d_in[25];
  const float* gate_W1   = (const float*)d_in[26];
  const float* gate_b1   = (const float*)d_in[27];
  const float* gate_W2   = (const float*)d_in[28];
  const float* gate_b2   = (const float*)d_in[29];
  const float* fc_W      = (const float*)d_in[30];
  const float* fc_b      = (const float*)d_in[31];
  (void)n_in; (void)ws_size;

  const int V  = in_sizes[5] / H;          // 50000
  const int ND = out_size / (NB * V);      // 8
  const int M  = NB * ND;                  // 1024 logits rows

  float* OUT = (float*)d_out;
  // d_out doubles as scratch for everything dead before the logits pass.
  size_t oP    = 0;                                // P: V*384 bf16 = V*192 floats
  size_t oEMBQ = (size_t)V * 192;
  size_t oQGI  = oEMBQ + (size_t)NB*TQ*H;
  size_t oGIAT = oQGI  + (size_t)NB*TQ*192;
  size_t oU1   = oGIAT + (size_t)NF*192;
  size_t oGATE = oU1   + (size_t)NF*H;
  short* Psh    = (short*)(OUT + oP);
  float* EMBQ   = OUT + oEMBQ;
  short* QGIsh  = (short*)(OUT + oQGI);
  short* GIATsh = (short*)(OUT + oGIAT);
  float* U1b    = OUT + oU1;
  float* GATE   = OUT + oGATE;

  float* encf = (float*)d_ws;              // NF*H
  float* qvec = encf + (size_t)NF*H;       // NB*H
  float* mem  = qvec + (size_t)NB*H;       // NB*H
  float* h2d  = mem  + (size_t)NB*H;       // M*H
  float* lse  = h2d  + (size_t)M*H;        // M
  float2* partials = (float2*)(lse + M);   // M*LSLICE float2

  // 1. fact-GRU input projection as bf16 vocab table
  k_mgemm_bf16<<<dim3((V+63)/64, H3/128), 256, 0, stream>>>(embed, ig_Wih, ig_bih, Psh, V, H3);
  // 2-3. question embeddings + projection (bf16 table)
  k_gather<<<NB*TQ, 128, 0, stream>>>(embed, questions, EMBQ);
  k_mgemm_bf16<<<dim3(NB*TQ/64, H3/128), 256, 0, stream>>>(EMBQ, qg_Wih, qg_bih, QGIsh, NB*TQ, H3);
  // 4. fact GRU scan
  k_recgru2<<<NF/16, 512, 0, stream>>>(Psh, facts, fmask, ig_Whh, ig_bhh, encf, TI);
  // 5. question GRU scan
  k_recgru2<<<NB/16, 512, 0, stream>>>(QGIsh, nullptr, qmask, qg_Whh, qg_bhh, qvec, TQ);
  // 6. attention-GRU input projection (bf16 table)
  k_mgemm_bf16<<<dim3(NF/64, H3/128), 256, 0, stream>>>(encf, at_Wih, at_bih, GIATsh, NF, H3);
  // 7. m-independent gate half
  k_gatepre<<<NF/16, 128, 0, stream>>>(encf, qvec, gate_W1, gate_b1, U1b);
  // 8. memory = q
  k_copy<<<(NB*H+255)/256, 256, 0, stream>>>(qvec, mem, NB*H);
  // 9. episodes
  for (int e = 0; e < EPISODES; ++e) {
    k_gate<<<NF/16, 128, 0, stream>>>(encf, mem, gate_W1, gate_W2, gate_b2, U1b, GATE);
    k_episode2<<<NB/16, 512, 0, stream>>>(GIATsh, GATE, at_Whh, at_bhh,
                                          me_Wih, me_Whh, me_bih, me_bhh, mem);
  }
  // 10. decoder recurrence
  k_decode<<<NB/2, 384, 0, stream>>>(embed, qvec, mem, an_Wih, an_Whh, an_bih, an_bhh,
                                     h2d, ND);
  // 11. log-softmax(h2 @ fc_W^T + fc_b): stats pass -> combine -> write pass
  k_lpass1<<<dim3(M/64, LSLICE), 256, 0, stream>>>(h2d, fc_W, fc_b, partials, M, V);
  k_lse<<<(M+255)/256, 256, 0, stream>>>(partials, lse, M);
  k_lpass2<<<dim3(M/64, (V+127)/128), 256, 0, stream>>>(h2d, fc_W, fc_b, lse, OUT, M, V);
}